// Round 14
// baseline (64.224 us; speedup 1.0000x reference)
//
#include <hip/hip_runtime.h>

#define S_LEN 4096
#define DH 64
#define SPAN 512
#define FIXED_M 8.0f

typedef _Float16 f16x8 __attribute__((ext_vector_type(8)));
typedef __fp16 fp16v2 __attribute__((ext_vector_type(2)));
typedef float f32x4 __attribute__((ext_vector_type(4)));

#define MFMA16 __builtin_amdgcn_mfma_f32_16x16x32_f16

__device__ __forceinline__ f16x8 load_cvt8(const float* __restrict__ p) {
  float4 a = *(const float4*)p;
  float4 b = *(const float4*)(p + 4);
  f16x8 r;
  r[0] = (_Float16)a.x; r[1] = (_Float16)a.y; r[2] = (_Float16)a.z; r[3] = (_Float16)a.w;
  r[4] = (_Float16)b.x; r[5] = (_Float16)b.y; r[6] = (_Float16)b.z; r[7] = (_Float16)b.w;
  return r;
}

// ---------------- pre-pass: fragment-ordered K and V ----------------
__global__ __launch_bounds__(256) void prep_frag(const float* __restrict__ k,
                                                 const float* __restrict__ v,
                                                 _Float16* __restrict__ KF,
                                                 _Float16* __restrict__ VF) {
  const int b = blockIdx.x;            // 0..1023
  const int h = b >> 7, tile = b & 127;
  const int kv0 = tile * 32;
  __shared__ _Float16 LK[32][64];      // [kv][d]
  __shared__ _Float16 LV[64][36];      // [d][kv], padded
  const int t = threadIdx.x;
  const int row = t >> 3, cb = (t & 7) * 8;
  {
    const float* kp = k + ((size_t)h * S_LEN + kv0 + row) * DH + cb;
    float4 a = *(const float4*)kp;
    float4 bq = *(const float4*)(kp + 4);
    LK[row][cb + 0] = (_Float16)a.x;  LK[row][cb + 1] = (_Float16)a.y;
    LK[row][cb + 2] = (_Float16)a.z;  LK[row][cb + 3] = (_Float16)a.w;
    LK[row][cb + 4] = (_Float16)bq.x; LK[row][cb + 5] = (_Float16)bq.y;
    LK[row][cb + 6] = (_Float16)bq.z; LK[row][cb + 7] = (_Float16)bq.w;
  }
  {
    const float* vp = v + ((size_t)h * S_LEN + kv0 + row) * DH + cb;
    float4 a = *(const float4*)vp;
    float4 bq = *(const float4*)(vp + 4);
    LV[cb + 0][row] = (_Float16)a.x;  LV[cb + 1][row] = (_Float16)a.y;
    LV[cb + 2][row] = (_Float16)a.z;  LV[cb + 3][row] = (_Float16)a.w;
    LV[cb + 4][row] = (_Float16)bq.x; LV[cb + 5][row] = (_Float16)bq.y;
    LV[cb + 6][row] = (_Float16)bq.z; LV[cb + 7][row] = (_Float16)bq.w;
  }
  __syncthreads();
  const int l = t & 63, c = l & 15, g = l >> 4;
  const size_t tb = (size_t)(h * 128 + tile) * 2048;
  {
    const int ch = t >> 6;
    f16x8 r = *(const f16x8*)&LK[16 * (ch >> 1) + c][32 * (ch & 1) + 8 * g];
    *(f16x8*)(KF + tb + (size_t)(ch * 64 + l) * 8) = r;
  }
  {
    const int dd = t >> 6;
    f16x8 r;
    #pragma unroll
    for (int jj = 0; jj < 4; ++jj) {
      r[jj]     = LV[16 * dd + c][4 * g + jj];
      r[4 + jj] = LV[16 * dd + c][16 + 4 * g + jj];
    }
    *(f16x8*)(VF + tb + (size_t)(dd * 64 + l) * 8) = r;
  }
}

// ---------------- 4-group tile body: 64 q-rows per wave, one K/V load ----------------
// MODE: 0 = no mask (history), 1 = causal diag, 2 = spatial diag
template<int MODE>
__device__ __forceinline__ void kv_tile4(
    const _Float16* __restrict__ kbase, const _Float16* __restrict__ vbase,
    int kt, int q_base, int c, int g,
    const f16x8 (&qf)[4][2], float (&l_run)[4], f32x4 (&of)[4][4])
{
  const int toff = (kt >> 5) * 2048;   // f16 units
  f16x8 kf0a = *(const f16x8*)(kbase + toff);
  f16x8 kf0b = *(const f16x8*)(kbase + toff + 512);
  f16x8 kf1a = *(const f16x8*)(kbase + toff + 1024);
  f16x8 kf1b = *(const f16x8*)(kbase + toff + 1536);
  f16x8 vf0  = *(const f16x8*)(vbase + toff);
  f16x8 vf1  = *(const f16x8*)(vbase + toff + 512);
  f16x8 vf2  = *(const f16x8*)(vbase + toff + 1024);
  f16x8 vf3  = *(const f16x8*)(vbase + toff + 1536);

  const float SCL = 0.18033688011112042f;  // (1/sqrt(64)) * log2(e)

  #pragma unroll
  for (int grp = 0; grp < 4; ++grp) {
    f32x4 st0 = {0.f, 0.f, 0.f, 0.f};
    f32x4 st1 = {0.f, 0.f, 0.f, 0.f};
    st0 = MFMA16(kf0a, qf[grp][0], st0, 0, 0, 0);
    st0 = MFMA16(kf0b, qf[grp][1], st0, 0, 0, 0);
    st1 = MFMA16(kf1a, qf[grp][0], st1, 0, 0, 0);
    st1 = MFMA16(kf1b, qf[grp][1], st1, 0, 0, 0);
    // S^T[kv = kt + 16t + 4g + r][q = q_base + 16*grp + c]

    const int qg = q_base + 16 * grp + c;
    float p[8];
    #pragma unroll
    for (int t = 0; t < 2; ++t) {
      #pragma unroll
      for (int r = 0; r < 4; ++r) {
        float pe = __builtin_amdgcn_exp2f(fmaf(t ? st1[r] : st0[r], SCL, -FIXED_M));
        if (MODE == 1) {
          int kvi = kt + 16 * t + 4 * g + r;
          pe = (kvi <= qg) ? pe : 0.f;
        } else if (MODE == 2) {
          int kvi = kt + 16 * t + 4 * g + r;
          int pq = qg & (SPAN - 1), pk = kvi & (SPAN - 1);
          int dy = (pq >> 5) - (pk >> 5);
          int dx = (pq & 31) - (pk & 31);
          pe = (dy * dy + dx * dx <= 6) ? pe : 0.f;
        }
        p[4 * t + r] = pe;
      }
    }
    l_run[grp] += ((p[0] + p[1]) + (p[2] + p[3])) + ((p[4] + p[5]) + (p[6] + p[7]));

    union { unsigned int w[4]; f16x8 v; } u;
    union { fp16v2 h; unsigned int w; } t0, t1, t2, t3;
    t0.h = __builtin_amdgcn_cvt_pkrtz(p[0], p[1]);
    t1.h = __builtin_amdgcn_cvt_pkrtz(p[2], p[3]);
    t2.h = __builtin_amdgcn_cvt_pkrtz(p[4], p[5]);
    t3.h = __builtin_amdgcn_cvt_pkrtz(p[6], p[7]);
    u.w[0] = t0.w; u.w[1] = t1.w; u.w[2] = t2.w; u.w[3] = t3.w;
    f16x8 pa = u.v;

    of[grp][0] = MFMA16(vf0, pa, of[grp][0], 0, 0, 0);
    of[grp][1] = MFMA16(vf1, pa, of[grp][1], 0, 0, 0);
    of[grp][2] = MFMA16(vf2, pa, of[grp][2], 0, 0, 0);
    of[grp][3] = MFMA16(vf3, pa, of[grp][3], 0, 0, 0);
  }
}

// ---------------- main kernel: wave = (head, 64q strip, 512kv range) ----------------
// 288 units/head: hist span s has 8s units (8 subs x s chunks), diag 8x8.
// 2304 waves = 576 blocks x 4; block-mates share the kv chunk (L1 reuse).
// Partials (plain sums under fixed-M softmax) to slot (strip, slot<=s).
__global__ __launch_bounds__(256) void msa_attn14(
    const float* __restrict__ q, const _Float16* __restrict__ KF,
    const _Float16* __restrict__ VF, float* __restrict__ PO,
    float* __restrict__ PL)
{
  const int tid = threadIdx.x;
  const int lane = tid & 63, w = tid >> 6;
  const int c = lane & 15, g = lane >> 4;

  const int b = blockIdx.x;             // 0..575
  const int h = b & 7;                  // head -> XCD L2 affinity (r5/r7/r10)
  const int unit = (b >> 3) * 4 + w;    // 0..287

  int s, sub, slot, klo, khi, mode;
  {
    int r = unit;
    if (r < 224) {
      s = 1;
      while (r >= 8 * s) { r -= 8 * s; ++s; }
      sub = r & 7;
      slot = r >> 3;                    // hist chunk 0..s-1
      klo = slot << 9;
      khi = klo + 512;
      mode = 0;
    } else {
      r -= 224;
      s = r >> 3; sub = r & 7;
      slot = s;
      const int hist_end = s * SPAN;
      const int qb = s * SPAN + sub * 64;
      if ((s & 1) == 0) {
        klo = hist_end; khi = qb + 64; mode = 1;
      } else {
        klo = qb - 96; if (klo < hist_end) klo = hist_end;
        khi = qb + 160;
        const int s1 = hist_end + SPAN; if (khi > s1) khi = s1;
        mode = 2;
      }
    }
  }
  const int q_base = s * SPAN + sub * 64;

  const float* Qh = q + (size_t)h * S_LEN * DH;
  const _Float16* kbase = KF + (size_t)h * 262144 + (size_t)lane * 8;
  const _Float16* vbase = VF + (size_t)h * 262144 + (size_t)lane * 8;

  f16x8 qf[4][2];
  #pragma unroll
  for (int grp = 0; grp < 4; ++grp) {
    const float* qp = Qh + (size_t)(q_base + 16 * grp + c) * DH + 8 * g;
    qf[grp][0] = load_cvt8(qp);
    qf[grp][1] = load_cvt8(qp + 32);
  }

  float l_run[4] = {0.f, 0.f, 0.f, 0.f};
  f32x4 of[4][4];
  #pragma unroll
  for (int a = 0; a < 4; ++a)
    #pragma unroll
    for (int bb = 0; bb < 4; ++bb) of[a][bb] = (f32x4){0.f, 0.f, 0.f, 0.f};

  if (mode == 0) {
    for (int kt = klo; kt < khi; kt += 32)
      kv_tile4<0>(kbase, vbase, kt, q_base, c, g, qf, l_run, of);
  } else if (mode == 1) {
    for (int kt = klo; kt < khi; kt += 32)
      kv_tile4<1>(kbase, vbase, kt, q_base, c, g, qf, l_run, of);
  } else {
    for (int kt = klo; kt < khi; kt += 32)
      kv_tile4<2>(kbase, vbase, kt, q_base, c, g, qf, l_run, of);
  }

  // row-sum of l across the 4 g-groups (only cross-lane ops in kernel)
  #pragma unroll
  for (int grp = 0; grp < 4; ++grp) {
    l_run[grp] += __shfl_xor(l_run[grp], 16);
    l_run[grp] += __shfl_xor(l_run[grp], 32);
  }

  const size_t sl_idx = (size_t)(h * 64 + s * 8 + sub) * 8 + slot;
  float* po = PO + sl_idx * 4096;
  float* pl = PL + sl_idx * 64;
  if (g == 0) {
    pl[c] = l_run[0]; pl[16 + c] = l_run[1];
    pl[32 + c] = l_run[2]; pl[48 + c] = l_run[3];
  }
  #pragma unroll
  for (int grp = 0; grp < 4; ++grp)
    #pragma unroll
    for (int dd = 0; dd < 4; ++dd)
      *(f32x4*)(po + (16 * grp + c) * 64 + 16 * dd + 4 * g) = of[grp][dd];
}

// ---------------- finalize: deterministic slot sum + normalize ----------------
__global__ __launch_bounds__(256) void finalize14(const float* __restrict__ PO,
                                                  const float* __restrict__ PL,
                                                  float* __restrict__ out) {
  const int strip = blockIdx.x;         // 0..511
  const int h = strip >> 6, idx = strip & 63;
  const int s = idx >> 3, sub = idx & 7;
  const int t = threadIdx.x;
  const int row = t >> 2;               // 0..63
  const int colb = (t & 3) * 16;        // 0,16,32,48
  const float* po = PO + (size_t)strip * 8 * 4096 + row * 64 + colb;
  const float* pl = PL + (size_t)strip * 8 * 64 + row;
  f32x4 a0 = {0.f,0.f,0.f,0.f}, a1 = {0.f,0.f,0.f,0.f};
  f32x4 a2 = {0.f,0.f,0.f,0.f}, a3 = {0.f,0.f,0.f,0.f};
  float l = 0.f;
  for (int sl = 0; sl <= s; ++sl) {
    const float* p = po + sl * 4096;
    a0 += *(const f32x4*)(p);
    a1 += *(const f32x4*)(p + 4);
    a2 += *(const f32x4*)(p + 8);
    a3 += *(const f32x4*)(p + 12);
    l  += pl[sl * 64];
  }
  const float inv = 1.0f / l;
  const int orow = s * SPAN + sub * 64 + row;
  float* op = out + ((size_t)h * S_LEN + orow) * DH + colb;
  f32x4 o0, o1, o2, o3;
  #pragma unroll
  for (int j = 0; j < 4; ++j) {
    o0[j] = a0[j] * inv; o1[j] = a1[j] * inv;
    o2[j] = a2[j] * inv; o3[j] = a3[j] * inv;
  }
  *(f32x4*)op = o0;
  *(f32x4*)(op + 4) = o1;
  *(f32x4*)(op + 8) = o2;
  *(f32x4*)(op + 12) = o3;
}

// ---------------- 2-group tile body (for mid fallback) ----------------
template<int MODE>
__device__ __forceinline__ void kv_tile(
    const _Float16* __restrict__ kbase, const _Float16* __restrict__ vbase,
    int kt, int q_base, int c, int g,
    const f16x8 (&qf)[2][2], float (&l_run)[2], f32x4 (&of)[2][4])
{
  const int toff = (kt >> 5) * 2048;
  f16x8 kf0a = *(const f16x8*)(kbase + toff);
  f16x8 kf0b = *(const f16x8*)(kbase + toff + 512);
  f16x8 kf1a = *(const f16x8*)(kbase + toff + 1024);
  f16x8 kf1b = *(const f16x8*)(kbase + toff + 1536);
  f16x8 vf0  = *(const f16x8*)(vbase + toff);
  f16x8 vf1  = *(const f16x8*)(vbase + toff + 512);
  f16x8 vf2  = *(const f16x8*)(vbase + toff + 1024);
  f16x8 vf3  = *(const f16x8*)(vbase + toff + 1536);

  const float SCL = 0.18033688011112042f;

  #pragma unroll
  for (int grp = 0; grp < 2; ++grp) {
    f32x4 st0 = {0.f, 0.f, 0.f, 0.f};
    f32x4 st1 = {0.f, 0.f, 0.f, 0.f};
    st0 = MFMA16(kf0a, qf[grp][0], st0, 0, 0, 0);
    st0 = MFMA16(kf0b, qf[grp][1], st0, 0, 0, 0);
    st1 = MFMA16(kf1a, qf[grp][0], st1, 0, 0, 0);
    st1 = MFMA16(kf1b, qf[grp][1], st1, 0, 0, 0);

    const int qg = q_base + 16 * grp + c;
    float p[8];
    #pragma unroll
    for (int t = 0; t < 2; ++t) {
      #pragma unroll
      for (int r = 0; r < 4; ++r) {
        float pe = __builtin_amdgcn_exp2f(fmaf(t ? st1[r] : st0[r], SCL, -FIXED_M));
        if (MODE == 1) {
          int kvi = kt + 16 * t + 4 * g + r;
          pe = (kvi <= qg) ? pe : 0.f;
        } else if (MODE == 2) {
          int kvi = kt + 16 * t + 4 * g + r;
          int pq = qg & (SPAN - 1), pk = kvi & (SPAN - 1);
          int dy = (pq >> 5) - (pk >> 5);
          int dx = (pq & 31) - (pk & 31);
          pe = (dy * dy + dx * dx <= 6) ? pe : 0.f;
        }
        p[4 * t + r] = pe;
      }
    }
    l_run[grp] += ((p[0] + p[1]) + (p[2] + p[3])) + ((p[4] + p[5]) + (p[6] + p[7]));

    union { unsigned int w[4]; f16x8 v; } u;
    union { fp16v2 h; unsigned int w; } t0, t1, t2, t3;
    t0.h = __builtin_amdgcn_cvt_pkrtz(p[0], p[1]);
    t1.h = __builtin_amdgcn_cvt_pkrtz(p[2], p[3]);
    t2.h = __builtin_amdgcn_cvt_pkrtz(p[4], p[5]);
    t3.h = __builtin_amdgcn_cvt_pkrtz(p[6], p[7]);
    u.w[0] = t0.w; u.w[1] = t1.w; u.w[2] = t2.w; u.w[3] = t3.w;
    f16x8 pa = u.v;

    of[grp][0] = MFMA16(vf0, pa, of[grp][0], 0, 0, 0);
    of[grp][1] = MFMA16(vf1, pa, of[grp][1], 0, 0, 0);
    of[grp][2] = MFMA16(vf2, pa, of[grp][2], 0, 0, 0);
    of[grp][3] = MFMA16(vf3, pa, of[grp][3], 0, 0, 0);
  }
}

// ---------------- mid fallback: round-10 kernel (direct out, 8MB ws) ----------------
__global__ __launch_bounds__(256, 3) void msa_attn10(
    const float* __restrict__ q, const _Float16* __restrict__ KF,
    const _Float16* __restrict__ VF, float* __restrict__ out)
{
  const int tid = threadIdx.x;
  const int lane = tid & 63, w = tid >> 6;
  const int c = lane & 15, g = lane >> 4;

  const int i = blockIdx.x;
  const int h = i & 7;
  const int m = i >> 3;
  const int jj = m >> 5;
  const int sidx = ((m & 7) + jj) & 7;
  const int span = (sidx & 1) ? 7 - (sidx >> 1) : (sidx >> 1);
  const int sub = ((m >> 3) & 3) * 4 + jj;
  const int q_base = span * SPAN + sub * 32;

  const float* Qh = q + (size_t)h * S_LEN * DH;
  const _Float16* kbase = KF + (size_t)h * 262144 + (size_t)lane * 8;
  const _Float16* vbase = VF + (size_t)h * 262144 + (size_t)lane * 8;
  float* Oh = out + (size_t)h * S_LEN * DH;

  f16x8 qf[2][2];
  #pragma unroll
  for (int grp = 0; grp < 2; ++grp) {
    const float* qp = Qh + (size_t)(q_base + 16 * grp + c) * DH + 8 * g;
    qf[grp][0] = load_cvt8(qp);
    qf[grp][1] = load_cvt8(qp + 32);
  }

  float l_run[2] = {0.f, 0.f};
  f32x4 of[2][4];
  #pragma unroll
  for (int a = 0; a < 2; ++a)
    #pragma unroll
    for (int bb = 0; bb < 4; ++bb) of[a][bb] = (f32x4){0.f, 0.f, 0.f, 0.f};

  const int hist_end = span * SPAN;
  for (int kt = 32 * w; kt < hist_end; kt += 128)
    kv_tile<0>(kbase, vbase, kt, q_base, c, g, qf, l_run, of);

  if ((span & 1) == 0) {
    for (int kt = hist_end + 32 * w; kt < q_base + 32; kt += 128)
      kv_tile<1>(kbase, vbase, kt, q_base, c, g, qf, l_run, of);
  } else {
    int klo = q_base - 96;
    if (klo < hist_end) klo = hist_end;
    int khi = q_base + 128;
    const int s1 = hist_end + SPAN;
    if (khi > s1) khi = s1;
    for (int kt = klo + 32 * w; kt < khi; kt += 128)
      kv_tile<2>(kbase, vbase, kt, q_base, c, g, qf, l_run, of);
  }

  #pragma unroll
  for (int grp = 0; grp < 2; ++grp) {
    l_run[grp] += __shfl_xor(l_run[grp], 16);
    l_run[grp] += __shfl_xor(l_run[grp], 32);
  }

  __shared__ float sl[4][2][16];
  __shared__ float sof[4][2][4][16][17];
  if (g == 0) { sl[w][0][c] = l_run[0]; sl[w][1][c] = l_run[1]; }
  #pragma unroll
  for (int grp = 0; grp < 2; ++grp)
    #pragma unroll
    for (int dd = 0; dd < 4; ++dd)
      #pragma unroll
      for (int r = 0; r < 4; ++r)
        sof[w][grp][dd][4 * g + r][c] = of[grp][dd][r];
  __syncthreads();

  const int mc = tid & 15, mgrp = (tid >> 4) & 1, mdd = (tid >> 5) & 3;
  const int mhalf = tid >> 7;
  float ls = sl[0][mgrp][mc] + sl[1][mgrp][mc] + sl[2][mgrp][mc] + sl[3][mgrp][mc];
  float inv = 1.0f / ls;
  const int row = q_base + 16 * mgrp + mc;
  #pragma unroll
  for (int dbi = 0; dbi < 2; ++dbi) {
    const int db = 2 * mhalf + dbi;
    f32x4 o4;
    #pragma unroll
    for (int j = 0; j < 4; ++j) {
      int dc = db * 4 + j;
      o4[j] = (sof[0][mgrp][mdd][dc][mc] + sof[1][mgrp][mdd][dc][mc]
             + sof[2][mgrp][mdd][dc][mc] + sof[3][mgrp][mdd][dc][mc]) * inv;
    }
    *(f32x4*)(Oh + (size_t)row * DH + mdd * 16 + db * 4) = o4;
  }
}

// ---------------- last-resort fallback (round-1, f32 direct) ----------------
template<int MODE>
__device__ __forceinline__ void kv_tile_fb(
    const float* __restrict__ Kh, const float* __restrict__ Vh,
    int kt, int qg_row, int c, int g,
    const f16x8 (&qf)[2], float& m_run, float& l_run, f32x4 (&of)[4])
{
  f16x8 kf0a = load_cvt8(Kh + (kt +      c) * DH + 8 * g);
  f16x8 kf0b = load_cvt8(Kh + (kt +      c) * DH + 8 * g + 32);
  f16x8 kf1a = load_cvt8(Kh + (kt + 16 + c) * DH + 8 * g);
  f16x8 kf1b = load_cvt8(Kh + (kt + 16 + c) * DH + 8 * g + 32);

  f32x4 st0 = {0.f, 0.f, 0.f, 0.f};
  f32x4 st1 = {0.f, 0.f, 0.f, 0.f};
  st0 = MFMA16(kf0a, qf[0], st0, 0, 0, 0);
  st0 = MFMA16(kf0b, qf[1], st0, 0, 0, 0);
  st1 = MFMA16(kf1a, qf[0], st1, 0, 0, 0);
  st1 = MFMA16(kf1b, qf[1], st1, 0, 0, 0);

  const float SCL = 0.18033688011112042f;
  float ss[8];
  #pragma unroll
  for (int t = 0; t < 2; ++t) {
    #pragma unroll
    for (int r = 0; r < 4; ++r) {
      float vsc = (t ? st1[r] : st0[r]) * SCL;
      if (MODE == 1) {
        int kv = kt + 16 * t + 4 * g + r;
        vsc = (kv <= qg_row) ? vsc : -1e30f;
      } else if (MODE == 2) {
        int kv = kt + 16 * t + 4 * g + r;
        int pq = qg_row & (SPAN - 1), pk = kv & (SPAN - 1);
        int dy = (pq >> 5) - (pk >> 5);
        int dx = (pq & 31) - (pk & 31);
        vsc = (dy * dy + dx * dx <= 6) ? vsc : -1e30f;
      }
      ss[t * 4 + r] = vsc;
    }
  }

  float pmax = ss[0];
  #pragma unroll
  for (int j = 1; j < 8; ++j) pmax = fmaxf(pmax, ss[j]);
  pmax = fmaxf(pmax, __shfl_xor(pmax, 16));
  pmax = fmaxf(pmax, __shfl_xor(pmax, 32));

  float m_new = fmaxf(m_run, pmax);
  float fac = exp2f(m_run - m_new);
  m_run = m_new;

  float p[8];
  float psum = 0.f;
  #pragma unroll
  for (int j = 0; j < 8; ++j) { p[j] = exp2f(ss[j] - m_new); psum += p[j]; }
  psum += __shfl_xor(psum, 16);
  psum += __shfl_xor(psum, 32);
  l_run = l_run * fac + psum;

  float fr0 = __shfl(fac, 4 * g + 0);
  float fr1 = __shfl(fac, 4 * g + 1);
  float fr2 = __shfl(fac, 4 * g + 2);
  float fr3 = __shfl(fac, 4 * g + 3);
  #pragma unroll
  for (int cc = 0; cc < 4; ++cc) {
    of[cc][0] *= fr0; of[cc][1] *= fr1; of[cc][2] *= fr2; of[cc][3] *= fr3;
  }

  f16x8 pa;
  #pragma unroll
  for (int j = 0; j < 8; ++j) pa[j] = (_Float16)p[j];

  #pragma unroll
  for (int cc = 0; cc < 4; ++cc) {
    f16x8 vb;
    #pragma unroll
    for (int j = 0; j < 8; ++j) {
      int kv = kt + ((j < 4) ? (4 * g + j) : (16 + 4 * g + (j - 4)));
      vb[j] = (_Float16)Vh[(size_t)kv * DH + 16 * cc + c];
    }
    of[cc] = MFMA16(pa, vb, of[cc], 0, 0, 0);
  }
}

__global__ __launch_bounds__(64) void msa_attn(
    const float* __restrict__ q, const float* __restrict__ k,
    const float* __restrict__ v, float* __restrict__ out)
{
  const int lane = threadIdx.x;
  const int c = lane & 15, g = lane >> 4;

  const int i = blockIdx.x;
  const int h = i & 7;
  const int grp = (i >> 3) & 31;
  const int t3 = i >> 8;
  const int span = (t3 + grp) & 7;
  const int q_base = span * SPAN + grp * 16;

  const float* Qh = q + (size_t)h * S_LEN * DH;
  const float* Kh = k + (size_t)h * S_LEN * DH;
  const float* Vh = v + (size_t)h * S_LEN * DH;
  float* Oh = out + (size_t)h * S_LEN * DH;

  f16x8 qf[2];
  qf[0] = load_cvt8(Qh + (size_t)(q_base + c) * DH + 8 * g);
  qf[1] = load_cvt8(Qh + (size_t)(q_base + c) * DH + 8 * g + 32);

  float m_run = -1e30f, l_run = 0.f;
  f32x4 of[4] = {{0,0,0,0},{0,0,0,0},{0,0,0,0},{0,0,0,0}};
  const int qg_row = q_base + c;

  const int hist_end = span * SPAN;
  for (int kt = 0; kt < hist_end; kt += 32)
    kv_tile_fb<0>(Kh, Vh, kt, qg_row, c, g, qf, m_run, l_run, of);

  const int s0 = hist_end;
  if ((span & 1) == 0) {
    const int khi = (q_base + 16 + 31) & ~31;
    for (int kt = s0; kt < khi; kt += 32)
      kv_tile_fb<1>(Kh, Vh, kt, qg_row, c, g, qf, m_run, l_run, of);
  } else {
    int klo = (q_base - 66) & ~31;
    if (klo < s0) klo = s0;
    int khi = (q_base + 81 + 32) & ~31;
    const int s1 = s0 + SPAN;
    if (khi > s1) khi = s1;
    for (int kt = klo; kt < khi; kt += 32)
      kv_tile_fb<2>(Kh, Vh, kt, qg_row, c, g, qf, m_run, l_run, of);
  }

  #pragma unroll
  for (int r = 0; r < 4; ++r) {
    float inv = 1.0f / __shfl(l_run, 4 * g + r);
    int row = q_base + 4 * g + r;
    #pragma unroll
    for (int cc = 0; cc < 4; ++cc)
      Oh[(size_t)row * DH + 16 * cc + c] = of[cc][r] * inv;
  }
}

extern "C" void kernel_launch(void* const* d_in, const int* in_sizes, int n_in,
                              void* d_out, int out_size, void* d_ws, size_t ws_size,
                              hipStream_t stream) {
  const float* q = (const float*)d_in[0];
  const float* k = (const float*)d_in[1];
  const float* v = (const float*)d_in[2];
  float* out = (float*)d_out;

  const size_t elems = (size_t)8 * S_LEN * DH;          // 2M f16 each
  const size_t kv_bytes = elems * 2 * 2;                // KF + VF = 8MB
  const size_t po_bytes = (size_t)512 * 8 * 4096 * 4;   // 64MB
  const size_t pl_bytes = (size_t)512 * 8 * 64 * 4;     // 1MB
  if (ws_size >= kv_bytes + po_bytes + pl_bytes) {
    _Float16* KF = (_Float16*)d_ws;
    _Float16* VF = KF + elems;
    float* PO = (float*)((char*)d_ws + kv_bytes);
    float* PL = (float*)((char*)d_ws + kv_bytes + po_bytes);
    prep_frag<<<dim3(1024), dim3(256), 0, stream>>>(k, v, KF, VF);
    msa_attn14<<<dim3(576), dim3(256), 0, stream>>>(q, KF, VF, PO, PL);
    finalize14<<<dim3(512), dim3(256), 0, stream>>>(PO, PL, out);
  } else if (ws_size >= kv_bytes) {
    _Float16* KF = (_Float16*)d_ws;
    _Float16* VF = KF + elems;
    prep_frag<<<dim3(1024), dim3(256), 0, stream>>>(k, v, KF, VF);
    msa_attn10<<<dim3(1024), dim3(256), 0, stream>>>(q, KF, VF, out);
  } else {
    msa_attn<<<dim3(2048), dim3(64), 0, stream>>>(q, k, v, out);
  }
}

// Round 15
// 62.789 us; speedup vs baseline: 1.0229x; 1.0229x over previous
//
#include <hip/hip_runtime.h>

#define S_LEN 4096
#define DH 64
#define SPAN 512
#define FIXED_M 8.0f

typedef _Float16 f16x8 __attribute__((ext_vector_type(8)));
typedef __fp16 fp16v2 __attribute__((ext_vector_type(2)));
typedef float f32x4 __attribute__((ext_vector_type(4)));

#define MFMA16 __builtin_amdgcn_mfma_f32_16x16x32_f16

__device__ __forceinline__ f16x8 load_cvt8(const float* __restrict__ p) {
  float4 a = *(const float4*)p;
  float4 b = *(const float4*)(p + 4);
  f16x8 r;
  r[0] = (_Float16)a.x; r[1] = (_Float16)a.y; r[2] = (_Float16)a.z; r[3] = (_Float16)a.w;
  r[4] = (_Float16)b.x; r[5] = (_Float16)b.y; r[6] = (_Float16)b.z; r[7] = (_Float16)b.w;
  return r;
}

// ---------------- pre-pass: fragment-ordered K and V ----------------
__global__ __launch_bounds__(256) void prep_frag(const float* __restrict__ k,
                                                 const float* __restrict__ v,
                                                 _Float16* __restrict__ KF,
                                                 _Float16* __restrict__ VF) {
  const int b = blockIdx.x;            // 0..1023
  const int h = b >> 7, tile = b & 127;
  const int kv0 = tile * 32;
  __shared__ _Float16 LK[32][64];      // [kv][d]
  __shared__ _Float16 LV[64][36];      // [d][kv], padded
  const int t = threadIdx.x;
  const int row = t >> 3, cb = (t & 7) * 8;
  {
    const float* kp = k + ((size_t)h * S_LEN + kv0 + row) * DH + cb;
    float4 a = *(const float4*)kp;
    float4 bq = *(const float4*)(kp + 4);
    LK[row][cb + 0] = (_Float16)a.x;  LK[row][cb + 1] = (_Float16)a.y;
    LK[row][cb + 2] = (_Float16)a.z;  LK[row][cb + 3] = (_Float16)a.w;
    LK[row][cb + 4] = (_Float16)bq.x; LK[row][cb + 5] = (_Float16)bq.y;
    LK[row][cb + 6] = (_Float16)bq.z; LK[row][cb + 7] = (_Float16)bq.w;
  }
  {
    const float* vp = v + ((size_t)h * S_LEN + kv0 + row) * DH + cb;
    float4 a = *(const float4*)vp;
    float4 bq = *(const float4*)(vp + 4);
    LV[cb + 0][row] = (_Float16)a.x;  LV[cb + 1][row] = (_Float16)a.y;
    LV[cb + 2][row] = (_Float16)a.z;  LV[cb + 3][row] = (_Float16)a.w;
    LV[cb + 4][row] = (_Float16)bq.x; LV[cb + 5][row] = (_Float16)bq.y;
    LV[cb + 6][row] = (_Float16)bq.z; LV[cb + 7][row] = (_Float16)bq.w;
  }
  __syncthreads();
  const int l = t & 63, c = l & 15, g = l >> 4;
  const size_t tb = (size_t)(h * 128 + tile) * 2048;
  {
    const int ch = t >> 6;
    f16x8 r = *(const f16x8*)&LK[16 * (ch >> 1) + c][32 * (ch & 1) + 8 * g];
    *(f16x8*)(KF + tb + (size_t)(ch * 64 + l) * 8) = r;
  }
  {
    const int dd = t >> 6;
    f16x8 r;
    #pragma unroll
    for (int jj = 0; jj < 4; ++jj) {
      r[jj]     = LV[16 * dd + c][4 * g + jj];
      r[4 + jj] = LV[16 * dd + c][16 + 4 * g + jj];
    }
    *(f16x8*)(VF + tb + (size_t)(dd * 64 + l) * 8) = r;
  }
}

// ---------------- LDS-sourced tile body (2 q-groups = 32 q-rows) ----------------
// MODE: 0 = no mask (history), 1 = causal diag, 2 = spatial diag
template<int MODE>
__device__ __forceinline__ void tile_lds(
    const _Float16* kb, const _Float16* vb,   // LDS tile bases (2048 f16 each)
    int kt, int q_base, int c, int g, int lane,
    const f16x8 (&qf)[2][2], float (&l_run)[2], f32x4 (&of)[2][4])
{
  const _Float16* kp = kb + lane * 8;
  f16x8 kf0a = *(const f16x8*)(kp);
  f16x8 kf0b = *(const f16x8*)(kp + 512);
  f16x8 kf1a = *(const f16x8*)(kp + 1024);
  f16x8 kf1b = *(const f16x8*)(kp + 1536);
  const _Float16* vp = vb + lane * 8;
  f16x8 vf0  = *(const f16x8*)(vp);
  f16x8 vf1  = *(const f16x8*)(vp + 512);
  f16x8 vf2  = *(const f16x8*)(vp + 1024);
  f16x8 vf3  = *(const f16x8*)(vp + 1536);

  const float SCL = 0.18033688011112042f;  // (1/sqrt(64)) * log2(e)

  #pragma unroll
  for (int grp = 0; grp < 2; ++grp) {
    f32x4 st0 = {0.f, 0.f, 0.f, 0.f};
    f32x4 st1 = {0.f, 0.f, 0.f, 0.f};
    st0 = MFMA16(kf0a, qf[grp][0], st0, 0, 0, 0);
    st0 = MFMA16(kf0b, qf[grp][1], st0, 0, 0, 0);
    st1 = MFMA16(kf1a, qf[grp][0], st1, 0, 0, 0);
    st1 = MFMA16(kf1b, qf[grp][1], st1, 0, 0, 0);
    // S^T[kv = kt + 16t + 4g + r][q = q_base + 16*grp + c]

    const int qg = q_base + 16 * grp + c;
    float p[8];
    #pragma unroll
    for (int t = 0; t < 2; ++t) {
      #pragma unroll
      for (int r = 0; r < 4; ++r) {
        float pe = __builtin_amdgcn_exp2f(fmaf(t ? st1[r] : st0[r], SCL, -FIXED_M));
        if (MODE == 1) {
          int kvi = kt + 16 * t + 4 * g + r;
          pe = (kvi <= qg) ? pe : 0.f;
        } else if (MODE == 2) {
          int kvi = kt + 16 * t + 4 * g + r;
          int pq = qg & (SPAN - 1), pk = kvi & (SPAN - 1);
          int dy = (pq >> 5) - (pk >> 5);
          int dx = (pq & 31) - (pk & 31);
          pe = (dy * dy + dx * dx <= 6) ? pe : 0.f;
        }
        p[4 * t + r] = pe;
      }
    }
    l_run[grp] += ((p[0] + p[1]) + (p[2] + p[3])) + ((p[4] + p[5]) + (p[6] + p[7]));

    union { unsigned int w[4]; f16x8 v; } u;
    union { fp16v2 h; unsigned int w; } t0, t1, t2, t3;
    t0.h = __builtin_amdgcn_cvt_pkrtz(p[0], p[1]);
    t1.h = __builtin_amdgcn_cvt_pkrtz(p[2], p[3]);
    t2.h = __builtin_amdgcn_cvt_pkrtz(p[4], p[5]);
    t3.h = __builtin_amdgcn_cvt_pkrtz(p[6], p[7]);
    u.w[0] = t0.w; u.w[1] = t1.w; u.w[2] = t2.w; u.w[3] = t3.w;
    f16x8 pa = u.v;

    of[grp][0] = MFMA16(vf0, pa, of[grp][0], 0, 0, 0);
    of[grp][1] = MFMA16(vf1, pa, of[grp][1], 0, 0, 0);
    of[grp][2] = MFMA16(vf2, pa, of[grp][2], 0, 0, 0);
    of[grp][3] = MFMA16(vf3, pa, of[grp][3], 0, 0, 0);
  }
}

// ---------------- main: block = (h, sub-quad, kv chunk); LDS double-buffer ----------
// 144 quad-units/head: hist: span s has 4 quads x s chunks (112); diag: 4x8 (32).
// The 4 waves share the chunk's K/V tiles via LDS (issue-early/write-late staging);
// each wave owns sub = quad*4 + w (32 q rows). Partials to slot (strip, slot<=s).
__global__ __launch_bounds__(256) void msa_attn15(
    const float* __restrict__ q, const _Float16* __restrict__ KF,
    const _Float16* __restrict__ VF, float* __restrict__ PO,
    float* __restrict__ PL)
{
  const int tid = threadIdx.x;
  const int lane = tid & 63, w = tid >> 6;
  const int c = lane & 15, g = lane >> 4;

  const int b = blockIdx.x;             // 0..1151
  const int h = b & 7;                  // head -> XCD L2 affinity
  int r = b >> 3;                       // 0..143

  int s, quad, slot, klo, khi, mode;
  if (r < 112) {
    s = 1;
    while (r >= 4 * s) { r -= 4 * s; ++s; }
    quad = r & 3; slot = r >> 2;
    klo = slot << 9; khi = klo + 512;
    mode = 0;
  } else {
    r -= 112;
    s = r >> 2; quad = r & 3;
    slot = s;
    const int he = s * SPAN;
    const int qb0 = he + quad * 128;
    if ((s & 1) == 0) {
      klo = he; khi = qb0 + 128; mode = 1;
    } else {
      klo = qb0 - 96; if (klo < he) klo = he;
      khi = qb0 + 256;
      const int s1 = he + SPAN; if (khi > s1) khi = s1;
      mode = 2;
    }
  }
  const int sub = quad * 4 + w;
  const int q_base = s * SPAN + sub * 32;

  const float* Qh = q + (size_t)h * S_LEN * DH;
  const _Float16* KFh = KF + (size_t)h * 262144;
  const _Float16* VFh = VF + (size_t)h * 262144;

  __shared__ _Float16 KBUF[2][2048];
  __shared__ _Float16 VBUF[2][2048];

  f16x8 qf[2][2];
  #pragma unroll
  for (int grp = 0; grp < 2; ++grp) {
    const float* qp = Qh + (size_t)(q_base + 16 * grp + c) * DH + 8 * g;
    qf[grp][0] = load_cvt8(qp);
    qf[grp][1] = load_cvt8(qp + 32);
  }

  float l_run[2] = {0.f, 0.f};
  f32x4 of[2][4];
  #pragma unroll
  for (int a = 0; a < 2; ++a)
    #pragma unroll
    for (int bb = 0; bb < 4; ++bb) of[a][bb] = (f32x4){0.f, 0.f, 0.f, 0.f};

  // prologue: stage tile klo into buffer 0
  {
    const int toff = (klo >> 5) * 2048 + tid * 8;
    f16x8 kr = *(const f16x8*)(KFh + toff);
    f16x8 vr = *(const f16x8*)(VFh + toff);
    *(f16x8*)&KBUF[0][tid * 8] = kr;
    *(f16x8*)&VBUF[0][tid * 8] = vr;
  }
  __syncthreads();

  int cur = 0;
  for (int kt = klo; kt < khi; kt += 32) {
    const bool more = (kt + 32 < khi);   // block-uniform
    f16x8 kr, vr;
    if (more) {
      // issue-early: next tile global -> regs (latency hides under compute)
      const int toff = ((kt + 32) >> 5) * 2048 + tid * 8;
      kr = *(const f16x8*)(KFh + toff);
      vr = *(const f16x8*)(VFh + toff);
    }

    if (mode == 0)      tile_lds<0>(KBUF[cur], VBUF[cur], kt, q_base, c, g, lane, qf, l_run, of);
    else if (mode == 1) tile_lds<1>(KBUF[cur], VBUF[cur], kt, q_base, c, g, lane, qf, l_run, of);
    else                tile_lds<2>(KBUF[cur], VBUF[cur], kt, q_base, c, g, lane, qf, l_run, of);

    if (more) {
      // write-late: vmcnt wait lands here, after the compute phase
      *(f16x8*)&KBUF[cur ^ 1][tid * 8] = kr;
      *(f16x8*)&VBUF[cur ^ 1][tid * 8] = vr;
    }
    __syncthreads();
    cur ^= 1;
  }

  // row-sum of l across the 4 g-groups
  #pragma unroll
  for (int grp = 0; grp < 2; ++grp) {
    l_run[grp] += __shfl_xor(l_run[grp], 16);
    l_run[grp] += __shfl_xor(l_run[grp], 32);
  }

  const size_t sl_idx = (size_t)(h * 128 + s * 16 + sub) * 8 + slot;
  float* po = PO + sl_idx * 2048;
  float* pl = PL + sl_idx * 32;
  if (g == 0) { pl[c] = l_run[0]; pl[16 + c] = l_run[1]; }
  #pragma unroll
  for (int grp = 0; grp < 2; ++grp)
    #pragma unroll
    for (int dd = 0; dd < 4; ++dd)
      *(f32x4*)(po + (16 * grp + c) * 64 + 16 * dd + 4 * g) = of[grp][dd];
}

// ---------------- finalize: deterministic slot sum + normalize ----------------
__global__ __launch_bounds__(256) void finalize13(const float* __restrict__ PO,
                                                  const float* __restrict__ PL,
                                                  float* __restrict__ out) {
  const int strip = blockIdx.x;         // 0..1023
  const int h = strip >> 7, idx = strip & 127;
  const int s = idx >> 4, sub = idx & 15;
  const int t = threadIdx.x;
  const int row = t >> 3, colb = (t & 7) * 8;
  const float* po = PO + (size_t)strip * 8 * 2048 + row * 64 + colb;
  const float* pl = PL + (size_t)strip * 8 * 32 + row;
  f32x4 a0 = {0.f, 0.f, 0.f, 0.f}, a1 = {0.f, 0.f, 0.f, 0.f};
  float l = 0.f;
  for (int sl = 0; sl <= s; ++sl) {
    a0 += *(const f32x4*)(po + sl * 2048);
    a1 += *(const f32x4*)(po + sl * 2048 + 4);
    l  += pl[sl * 32];
  }
  const float inv = 1.0f / l;
  f32x4 o0, o1;
  #pragma unroll
  for (int j = 0; j < 4; ++j) { o0[j] = a0[j] * inv; o1[j] = a1[j] * inv; }
  const int orow = s * SPAN + sub * 32 + row;
  float* op = out + ((size_t)h * S_LEN + orow) * DH + colb;
  *(f32x4*)op = o0;
  *(f32x4*)(op + 4) = o1;
}

// ---------------- 2-group global tile body (for mid fallback) ----------------
template<int MODE>
__device__ __forceinline__ void kv_tile(
    const _Float16* __restrict__ kbase, const _Float16* __restrict__ vbase,
    int kt, int q_base, int c, int g,
    const f16x8 (&qf)[2][2], float (&l_run)[2], f32x4 (&of)[2][4])
{
  const int toff = (kt >> 5) * 2048;
  f16x8 kf0a = *(const f16x8*)(kbase + toff);
  f16x8 kf0b = *(const f16x8*)(kbase + toff + 512);
  f16x8 kf1a = *(const f16x8*)(kbase + toff + 1024);
  f16x8 kf1b = *(const f16x8*)(kbase + toff + 1536);
  f16x8 vf0  = *(const f16x8*)(vbase + toff);
  f16x8 vf1  = *(const f16x8*)(vbase + toff + 512);
  f16x8 vf2  = *(const f16x8*)(vbase + toff + 1024);
  f16x8 vf3  = *(const f16x8*)(vbase + toff + 1536);

  const float SCL = 0.18033688011112042f;

  #pragma unroll
  for (int grp = 0; grp < 2; ++grp) {
    f32x4 st0 = {0.f, 0.f, 0.f, 0.f};
    f32x4 st1 = {0.f, 0.f, 0.f, 0.f};
    st0 = MFMA16(kf0a, qf[grp][0], st0, 0, 0, 0);
    st0 = MFMA16(kf0b, qf[grp][1], st0, 0, 0, 0);
    st1 = MFMA16(kf1a, qf[grp][0], st1, 0, 0, 0);
    st1 = MFMA16(kf1b, qf[grp][1], st1, 0, 0, 0);

    const int qg = q_base + 16 * grp + c;
    float p[8];
    #pragma unroll
    for (int t = 0; t < 2; ++t) {
      #pragma unroll
      for (int r = 0; r < 4; ++r) {
        float pe = __builtin_amdgcn_exp2f(fmaf(t ? st1[r] : st0[r], SCL, -FIXED_M));
        if (MODE == 1) {
          int kvi = kt + 16 * t + 4 * g + r;
          pe = (kvi <= qg) ? pe : 0.f;
        } else if (MODE == 2) {
          int kvi = kt + 16 * t + 4 * g + r;
          int pq = qg & (SPAN - 1), pk = kvi & (SPAN - 1);
          int dy = (pq >> 5) - (pk >> 5);
          int dx = (pq & 31) - (pk & 31);
          pe = (dy * dy + dx * dx <= 6) ? pe : 0.f;
        }
        p[4 * t + r] = pe;
      }
    }
    l_run[grp] += ((p[0] + p[1]) + (p[2] + p[3])) + ((p[4] + p[5]) + (p[6] + p[7]));

    union { unsigned int w[4]; f16x8 v; } u;
    union { fp16v2 h; unsigned int w; } t0, t1, t2, t3;
    t0.h = __builtin_amdgcn_cvt_pkrtz(p[0], p[1]);
    t1.h = __builtin_amdgcn_cvt_pkrtz(p[2], p[3]);
    t2.h = __builtin_amdgcn_cvt_pkrtz(p[4], p[5]);
    t3.h = __builtin_amdgcn_cvt_pkrtz(p[6], p[7]);
    u.w[0] = t0.w; u.w[1] = t1.w; u.w[2] = t2.w; u.w[3] = t3.w;
    f16x8 pa = u.v;

    of[grp][0] = MFMA16(vf0, pa, of[grp][0], 0, 0, 0);
    of[grp][1] = MFMA16(vf1, pa, of[grp][1], 0, 0, 0);
    of[grp][2] = MFMA16(vf2, pa, of[grp][2], 0, 0, 0);
    of[grp][3] = MFMA16(vf3, pa, of[grp][3], 0, 0, 0);
  }
}

// ---------------- mid fallback: round-10 kernel (direct out, 8MB ws) ----------------
__global__ __launch_bounds__(256, 3) void msa_attn10(
    const float* __restrict__ q, const _Float16* __restrict__ KF,
    const _Float16* __restrict__ VF, float* __restrict__ out)
{
  const int tid = threadIdx.x;
  const int lane = tid & 63, w = tid >> 6;
  const int c = lane & 15, g = lane >> 4;

  const int i = blockIdx.x;
  const int h = i & 7;
  const int m = i >> 3;
  const int jj = m >> 5;
  const int sidx = ((m & 7) + jj) & 7;
  const int span = (sidx & 1) ? 7 - (sidx >> 1) : (sidx >> 1);
  const int sub = ((m >> 3) & 3) * 4 + jj;
  const int q_base = span * SPAN + sub * 32;

  const float* Qh = q + (size_t)h * S_LEN * DH;
  const _Float16* kbase = KF + (size_t)h * 262144 + (size_t)lane * 8;
  const _Float16* vbase = VF + (size_t)h * 262144 + (size_t)lane * 8;
  float* Oh = out + (size_t)h * S_LEN * DH;

  f16x8 qf[2][2];
  #pragma unroll
  for (int grp = 0; grp < 2; ++grp) {
    const float* qp = Qh + (size_t)(q_base + 16 * grp + c) * DH + 8 * g;
    qf[grp][0] = load_cvt8(qp);
    qf[grp][1] = load_cvt8(qp + 32);
  }

  float l_run[2] = {0.f, 0.f};
  f32x4 of[2][4];
  #pragma unroll
  for (int a = 0; a < 2; ++a)
    #pragma unroll
    for (int bb = 0; bb < 4; ++bb) of[a][bb] = (f32x4){0.f, 0.f, 0.f, 0.f};

  const int hist_end = span * SPAN;
  for (int kt = 32 * w; kt < hist_end; kt += 128)
    kv_tile<0>(kbase, vbase, kt, q_base, c, g, qf, l_run, of);

  if ((span & 1) == 0) {
    for (int kt = hist_end + 32 * w; kt < q_base + 32; kt += 128)
      kv_tile<1>(kbase, vbase, kt, q_base, c, g, qf, l_run, of);
  } else {
    int klo = q_base - 96;
    if (klo < hist_end) klo = hist_end;
    int khi = q_base + 128;
    const int s1 = hist_end + SPAN;
    if (khi > s1) khi = s1;
    for (int kt = klo + 32 * w; kt < khi; kt += 128)
      kv_tile<2>(kbase, vbase, kt, q_base, c, g, qf, l_run, of);
  }

  #pragma unroll
  for (int grp = 0; grp < 2; ++grp) {
    l_run[grp] += __shfl_xor(l_run[grp], 16);
    l_run[grp] += __shfl_xor(l_run[grp], 32);
  }

  __shared__ float sl[4][2][16];
  __shared__ float sof[4][2][4][16][17];
  if (g == 0) { sl[w][0][c] = l_run[0]; sl[w][1][c] = l_run[1]; }
  #pragma unroll
  for (int grp = 0; grp < 2; ++grp)
    #pragma unroll
    for (int dd = 0; dd < 4; ++dd)
      #pragma unroll
      for (int r = 0; r < 4; ++r)
        sof[w][grp][dd][4 * g + r][c] = of[grp][dd][r];
  __syncthreads();

  const int mc = tid & 15, mgrp = (tid >> 4) & 1, mdd = (tid >> 5) & 3;
  const int mhalf = tid >> 7;
  float ls = sl[0][mgrp][mc] + sl[1][mgrp][mc] + sl[2][mgrp][mc] + sl[3][mgrp][mc];
  float inv = 1.0f / ls;
  const int row = q_base + 16 * mgrp + mc;
  #pragma unroll
  for (int dbi = 0; dbi < 2; ++dbi) {
    const int db = 2 * mhalf + dbi;
    f32x4 o4;
    #pragma unroll
    for (int j = 0; j < 4; ++j) {
      int dc = db * 4 + j;
      o4[j] = (sof[0][mgrp][mdd][dc][mc] + sof[1][mgrp][mdd][dc][mc]
             + sof[2][mgrp][mdd][dc][mc] + sof[3][mgrp][mdd][dc][mc]) * inv;
    }
    *(f32x4*)(Oh + (size_t)row * DH + mdd * 16 + db * 4) = o4;
  }
}

// ---------------- last-resort fallback (round-1, f32 direct) ----------------
template<int MODE>
__device__ __forceinline__ void kv_tile_fb(
    const float* __restrict__ Kh, const float* __restrict__ Vh,
    int kt, int qg_row, int c, int g,
    const f16x8 (&qf)[2], float& m_run, float& l_run, f32x4 (&of)[4])
{
  f16x8 kf0a = load_cvt8(Kh + (kt +      c) * DH + 8 * g);
  f16x8 kf0b = load_cvt8(Kh + (kt +      c) * DH + 8 * g + 32);
  f16x8 kf1a = load_cvt8(Kh + (kt + 16 + c) * DH + 8 * g);
  f16x8 kf1b = load_cvt8(Kh + (kt + 16 + c) * DH + 8 * g + 32);

  f32x4 st0 = {0.f, 0.f, 0.f, 0.f};
  f32x4 st1 = {0.f, 0.f, 0.f, 0.f};
  st0 = MFMA16(kf0a, qf[0], st0, 0, 0, 0);
  st0 = MFMA16(kf0b, qf[1], st0, 0, 0, 0);
  st1 = MFMA16(kf1a, qf[0], st1, 0, 0, 0);
  st1 = MFMA16(kf1b, qf[1], st1, 0, 0, 0);

  const float SCL = 0.18033688011112042f;
  float ss[8];
  #pragma unroll
  for (int t = 0; t < 2; ++t) {
    #pragma unroll
    for (int r = 0; r < 4; ++r) {
      float vsc = (t ? st1[r] : st0[r]) * SCL;
      if (MODE == 1) {
        int kv = kt + 16 * t + 4 * g + r;
        vsc = (kv <= qg_row) ? vsc : -1e30f;
      } else if (MODE == 2) {
        int kv = kt + 16 * t + 4 * g + r;
        int pq = qg_row & (SPAN - 1), pk = kv & (SPAN - 1);
        int dy = (pq >> 5) - (pk >> 5);
        int dx = (pq & 31) - (pk & 31);
        vsc = (dy * dy + dx * dx <= 6) ? vsc : -1e30f;
      }
      ss[t * 4 + r] = vsc;
    }
  }

  float pmax = ss[0];
  #pragma unroll
  for (int j = 1; j < 8; ++j) pmax = fmaxf(pmax, ss[j]);
  pmax = fmaxf(pmax, __shfl_xor(pmax, 16));
  pmax = fmaxf(pmax, __shfl_xor(pmax, 32));

  float m_new = fmaxf(m_run, pmax);
  float fac = exp2f(m_run - m_new);
  m_run = m_new;

  float p[8];
  float psum = 0.f;
  #pragma unroll
  for (int j = 0; j < 8; ++j) { p[j] = exp2f(ss[j] - m_new); psum += p[j]; }
  psum += __shfl_xor(psum, 16);
  psum += __shfl_xor(psum, 32);
  l_run = l_run * fac + psum;

  float fr0 = __shfl(fac, 4 * g + 0);
  float fr1 = __shfl(fac, 4 * g + 1);
  float fr2 = __shfl(fac, 4 * g + 2);
  float fr3 = __shfl(fac, 4 * g + 3);
  #pragma unroll
  for (int cc = 0; cc < 4; ++cc) {
    of[cc][0] *= fr0; of[cc][1] *= fr1; of[cc][2] *= fr2; of[cc][3] *= fr3;
  }

  f16x8 pa;
  #pragma unroll
  for (int j = 0; j < 8; ++j) pa[j] = (_Float16)p[j];

  #pragma unroll
  for (int cc = 0; cc < 4; ++cc) {
    f16x8 vb;
    #pragma unroll
    for (int j = 0; j < 8; ++j) {
      int kv = kt + ((j < 4) ? (4 * g + j) : (16 + 4 * g + (j - 4)));
      vb[j] = (_Float16)Vh[(size_t)kv * DH + 16 * cc + c];
    }
    of[cc] = MFMA16(pa, vb, of[cc], 0, 0, 0);
  }
}

__global__ __launch_bounds__(64) void msa_attn(
    const float* __restrict__ q, const float* __restrict__ k,
    const float* __restrict__ v, float* __restrict__ out)
{
  const int lane = threadIdx.x;
  const int c = lane & 15, g = lane >> 4;

  const int i = blockIdx.x;
  const int h = i & 7;
  const int grp = (i >> 3) & 31;
  const int t3 = i >> 8;
  const int span = (t3 + grp) & 7;
  const int q_base = span * SPAN + grp * 16;

  const float* Qh = q + (size_t)h * S_LEN * DH;
  const float* Kh = k + (size_t)h * S_LEN * DH;
  const float* Vh = v + (size_t)h * S_LEN * DH;
  float* Oh = out + (size_t)h * S_LEN * DH;

  f16x8 qf[2];
  qf[0] = load_cvt8(Qh + (size_t)(q_base + c) * DH + 8 * g);
  qf[1] = load_cvt8(Qh + (size_t)(q_base + c) * DH + 8 * g + 32);

  float m_run = -1e30f, l_run = 0.f;
  f32x4 of[4] = {{0,0,0,0},{0,0,0,0},{0,0,0,0},{0,0,0,0}};
  const int qg_row = q_base + c;

  const int hist_end = span * SPAN;
  for (int kt = 0; kt < hist_end; kt += 32)
    kv_tile_fb<0>(Kh, Vh, kt, qg_row, c, g, qf, m_run, l_run, of);

  const int s0 = hist_end;
  if ((span & 1) == 0) {
    const int khi = (q_base + 16 + 31) & ~31;
    for (int kt = s0; kt < khi; kt += 32)
      kv_tile_fb<1>(Kh, Vh, kt, qg_row, c, g, qf, m_run, l_run, of);
  } else {
    int klo = (q_base - 66) & ~31;
    if (klo < s0) klo = s0;
    int khi = (q_base + 81 + 32) & ~31;
    const int s1 = s0 + SPAN;
    if (khi > s1) khi = s1;
    for (int kt = klo; kt < khi; kt += 32)
      kv_tile_fb<2>(Kh, Vh, kt, qg_row, c, g, qf, m_run, l_run, of);
  }

  #pragma unroll
  for (int r = 0; r < 4; ++r) {
    float inv = 1.0f / __shfl(l_run, 4 * g + r);
    int row = q_base + 4 * g + r;
    #pragma unroll
    for (int cc = 0; cc < 4; ++cc)
      Oh[(size_t)row * DH + 16 * cc + c] = of[cc][r] * inv;
  }
}

extern "C" void kernel_launch(void* const* d_in, const int* in_sizes, int n_in,
                              void* d_out, int out_size, void* d_ws, size_t ws_size,
                              hipStream_t stream) {
  const float* q = (const float*)d_in[0];
  const float* k = (const float*)d_in[1];
  const float* v = (const float*)d_in[2];
  float* out = (float*)d_out;

  const size_t elems = (size_t)8 * S_LEN * DH;          // 2M f16 each
  const size_t kv_bytes = elems * 2 * 2;                // KF + VF = 8MB
  const size_t po_bytes = (size_t)1024 * 8 * 2048 * 4;  // 64MB
  const size_t pl_bytes = (size_t)1024 * 8 * 32 * 4;    // 1MB
  if (ws_size >= kv_bytes + po_bytes + pl_bytes) {
    _Float16* KF = (_Float16*)d_ws;
    _Float16* VF = KF + elems;
    float* PO = (float*)((char*)d_ws + kv_bytes);
    float* PL = (float*)((char*)d_ws + kv_bytes + po_bytes);
    prep_frag<<<dim3(1024), dim3(256), 0, stream>>>(k, v, KF, VF);
    msa_attn15<<<dim3(1152), dim3(256), 0, stream>>>(q, KF, VF, PO, PL);
    finalize13<<<dim3(1024), dim3(256), 0, stream>>>(PO, PL, out);
  } else if (ws_size >= kv_bytes) {
    _Float16* KF = (_Float16*)d_ws;
    _Float16* VF = KF + elems;
    prep_frag<<<dim3(1024), dim3(256), 0, stream>>>(k, v, KF, VF);
    msa_attn10<<<dim3(1024), dim3(256), 0, stream>>>(q, KF, VF, out);
  } else {
    msa_attn<<<dim3(2048), dim3(64), 0, stream>>>(q, k, v, out);
  }
}

// Round 16
// 49.996 us; speedup vs baseline: 1.2846x; 1.2559x over previous
//
#include <hip/hip_runtime.h>

#define S_LEN 4096
#define DH 64
#define SPAN 512
#define FIXED_M 8.0f

typedef _Float16 f16x8 __attribute__((ext_vector_type(8)));
typedef __fp16 fp16v2 __attribute__((ext_vector_type(2)));
typedef float f32x4 __attribute__((ext_vector_type(4)));

#define MFMA16 __builtin_amdgcn_mfma_f32_16x16x32_f16

__device__ __forceinline__ f16x8 load_cvt8(const float* __restrict__ p) {
  float4 a = *(const float4*)p;
  float4 b = *(const float4*)(p + 4);
  f16x8 r;
  r[0] = (_Float16)a.x; r[1] = (_Float16)a.y; r[2] = (_Float16)a.z; r[3] = (_Float16)a.w;
  r[4] = (_Float16)b.x; r[5] = (_Float16)b.y; r[6] = (_Float16)b.z; r[7] = (_Float16)b.w;
  return r;
}

// ---------------- pre-pass: fragment-ordered K and V ----------------
__global__ __launch_bounds__(256) void prep_frag(const float* __restrict__ k,
                                                 const float* __restrict__ v,
                                                 _Float16* __restrict__ KF,
                                                 _Float16* __restrict__ VF) {
  const int b = blockIdx.x;            // 0..1023
  const int h = b >> 7, tile = b & 127;
  const int kv0 = tile * 32;
  __shared__ _Float16 LK[32][64];      // [kv][d]
  __shared__ _Float16 LV[64][36];      // [d][kv], padded
  const int t = threadIdx.x;
  const int row = t >> 3, cb = (t & 7) * 8;
  {
    const float* kp = k + ((size_t)h * S_LEN + kv0 + row) * DH + cb;
    float4 a = *(const float4*)kp;
    float4 bq = *(const float4*)(kp + 4);
    LK[row][cb + 0] = (_Float16)a.x;  LK[row][cb + 1] = (_Float16)a.y;
    LK[row][cb + 2] = (_Float16)a.z;  LK[row][cb + 3] = (_Float16)a.w;
    LK[row][cb + 4] = (_Float16)bq.x; LK[row][cb + 5] = (_Float16)bq.y;
    LK[row][cb + 6] = (_Float16)bq.z; LK[row][cb + 7] = (_Float16)bq.w;
  }
  {
    const float* vp = v + ((size_t)h * S_LEN + kv0 + row) * DH + cb;
    float4 a = *(const float4*)vp;
    float4 bq = *(const float4*)(vp + 4);
    LV[cb + 0][row] = (_Float16)a.x;  LV[cb + 1][row] = (_Float16)a.y;
    LV[cb + 2][row] = (_Float16)a.z;  LV[cb + 3][row] = (_Float16)a.w;
    LV[cb + 4][row] = (_Float16)bq.x; LV[cb + 5][row] = (_Float16)bq.y;
    LV[cb + 6][row] = (_Float16)bq.z; LV[cb + 7][row] = (_Float16)bq.w;
  }
  __syncthreads();
  const int l = t & 63, c = l & 15, g = l >> 4;
  const size_t tb = (size_t)(h * 128 + tile) * 2048;
  {
    const int ch = t >> 6;
    f16x8 r = *(const f16x8*)&LK[16 * (ch >> 1) + c][32 * (ch & 1) + 8 * g];
    *(f16x8*)(KF + tb + (size_t)(ch * 64 + l) * 8) = r;
  }
  {
    const int dd = t >> 6;
    f16x8 r;
    #pragma unroll
    for (int jj = 0; jj < 4; ++jj) {
      r[jj]     = LV[16 * dd + c][4 * g + jj];
      r[4 + jj] = LV[16 * dd + c][16 + 4 * g + jj];
    }
    *(f16x8*)(VF + tb + (size_t)(dd * 64 + l) * 8) = r;
  }
}

// ---------------- compute body from pre-loaded fragments ----------------
// MODE: 0 = no mask (history), 1 = causal diag, 2 = spatial diag
template<int MODE>
__device__ __forceinline__ void tile_compute(
    f16x8 kf0a, f16x8 kf0b, f16x8 kf1a, f16x8 kf1b,
    f16x8 vf0, f16x8 vf1, f16x8 vf2, f16x8 vf3,
    int kt, int q_base, int c, int g,
    const f16x8 (&qf)[2][2], float (&l_run)[2], f32x4 (&of)[2][4])
{
  const float SCL = 0.18033688011112042f;  // (1/sqrt(64)) * log2(e)

  #pragma unroll
  for (int grp = 0; grp < 2; ++grp) {
    f32x4 st0 = {0.f, 0.f, 0.f, 0.f};
    f32x4 st1 = {0.f, 0.f, 0.f, 0.f};
    st0 = MFMA16(kf0a, qf[grp][0], st0, 0, 0, 0);
    st0 = MFMA16(kf0b, qf[grp][1], st0, 0, 0, 0);
    st1 = MFMA16(kf1a, qf[grp][0], st1, 0, 0, 0);
    st1 = MFMA16(kf1b, qf[grp][1], st1, 0, 0, 0);
    // S^T[kv = kt + 16t + 4g + r][q = q_base + 16*grp + c]

    const int qg = q_base + 16 * grp + c;
    float p[8];
    #pragma unroll
    for (int t = 0; t < 2; ++t) {
      #pragma unroll
      for (int r = 0; r < 4; ++r) {
        float pe = __builtin_amdgcn_exp2f(fmaf(t ? st1[r] : st0[r], SCL, -FIXED_M));
        if (MODE == 1) {
          int kvi = kt + 16 * t + 4 * g + r;
          pe = (kvi <= qg) ? pe : 0.f;
        } else if (MODE == 2) {
          int kvi = kt + 16 * t + 4 * g + r;
          int pq = qg & (SPAN - 1), pk = kvi & (SPAN - 1);
          int dy = (pq >> 5) - (pk >> 5);
          int dx = (pq & 31) - (pk & 31);
          pe = (dy * dy + dx * dx <= 6) ? pe : 0.f;
        }
        p[4 * t + r] = pe;
      }
    }
    l_run[grp] += ((p[0] + p[1]) + (p[2] + p[3])) + ((p[4] + p[5]) + (p[6] + p[7]));

    union { unsigned int w[4]; f16x8 v; } u;
    union { fp16v2 h; unsigned int w; } t0, t1, t2, t3;
    t0.h = __builtin_amdgcn_cvt_pkrtz(p[0], p[1]);
    t1.h = __builtin_amdgcn_cvt_pkrtz(p[2], p[3]);
    t2.h = __builtin_amdgcn_cvt_pkrtz(p[4], p[5]);
    t3.h = __builtin_amdgcn_cvt_pkrtz(p[6], p[7]);
    u.w[0] = t0.w; u.w[1] = t1.w; u.w[2] = t2.w; u.w[3] = t3.w;
    f16x8 pa = u.v;

    of[grp][0] = MFMA16(vf0, pa, of[grp][0], 0, 0, 0);
    of[grp][1] = MFMA16(vf1, pa, of[grp][1], 0, 0, 0);
    of[grp][2] = MFMA16(vf2, pa, of[grp][2], 0, 0, 0);
    of[grp][3] = MFMA16(vf3, pa, of[grp][3], 0, 0, 0);
  }
}

// single tile: load + compute
template<int MODE>
__device__ __forceinline__ void kv_tile(
    const _Float16* __restrict__ kbase, const _Float16* __restrict__ vbase,
    int kt, int q_base, int c, int g,
    const f16x8 (&qf)[2][2], float (&l_run)[2], f32x4 (&of)[2][4])
{
  const int toff = (kt >> 5) * 2048;
  f16x8 ka = *(const f16x8*)(kbase + toff);
  f16x8 kb = *(const f16x8*)(kbase + toff + 512);
  f16x8 kc = *(const f16x8*)(kbase + toff + 1024);
  f16x8 kd = *(const f16x8*)(kbase + toff + 1536);
  f16x8 va = *(const f16x8*)(vbase + toff);
  f16x8 vb = *(const f16x8*)(vbase + toff + 512);
  f16x8 vc = *(const f16x8*)(vbase + toff + 1024);
  f16x8 vd = *(const f16x8*)(vbase + toff + 1536);
  tile_compute<MODE>(ka, kb, kc, kd, va, vb, vc, vd, kt, q_base, c, g, qf, l_run, of);
}

// pair of tiles (this wave's consecutive iterations, stride 128): all 16 loads
// issued up-front (2x memory-level parallelism), flat named vars (no arrays/structs
// -> no scratch, rounds 8/9 lesson). Same accumulation order as sequential.
template<int MODE>
__device__ __forceinline__ void kv_tile_pair(
    const _Float16* __restrict__ kbase, const _Float16* __restrict__ vbase,
    int kt, int q_base, int c, int g,
    const f16x8 (&qf)[2][2], float (&l_run)[2], f32x4 (&of)[2][4])
{
  const int toffA = (kt >> 5) * 2048;
  const int toffB = toffA + 8192;        // kt + 128
  f16x8 ka0 = *(const f16x8*)(kbase + toffA);
  f16x8 kb0 = *(const f16x8*)(kbase + toffA + 512);
  f16x8 kc0 = *(const f16x8*)(kbase + toffA + 1024);
  f16x8 kd0 = *(const f16x8*)(kbase + toffA + 1536);
  f16x8 va0 = *(const f16x8*)(vbase + toffA);
  f16x8 vb0 = *(const f16x8*)(vbase + toffA + 512);
  f16x8 vc0 = *(const f16x8*)(vbase + toffA + 1024);
  f16x8 vd0 = *(const f16x8*)(vbase + toffA + 1536);
  f16x8 ka1 = *(const f16x8*)(kbase + toffB);
  f16x8 kb1 = *(const f16x8*)(kbase + toffB + 512);
  f16x8 kc1 = *(const f16x8*)(kbase + toffB + 1024);
  f16x8 kd1 = *(const f16x8*)(kbase + toffB + 1536);
  f16x8 va1 = *(const f16x8*)(vbase + toffB);
  f16x8 vb1 = *(const f16x8*)(vbase + toffB + 512);
  f16x8 vc1 = *(const f16x8*)(vbase + toffB + 1024);
  f16x8 vd1 = *(const f16x8*)(vbase + toffB + 1536);
  tile_compute<MODE>(ka0, kb0, kc0, kd0, va0, vb0, vc0, vd0, kt, q_base, c, g, qf, l_run, of);
  tile_compute<MODE>(ka1, kb1, kc1, kd1, va1, vb1, vc1, vd1, kt + 128, q_base, c, g, qf, l_run, of);
}

// range runner: wave-strided (128), unrolled x2 for MLP, tail-safe
template<int MODE>
__device__ __forceinline__ void run_range(
    const _Float16* __restrict__ kbase, const _Float16* __restrict__ vbase,
    int klo, int khi, int q_base, int c, int g,
    const f16x8 (&qf)[2][2], float (&l_run)[2], f32x4 (&of)[2][4])
{
  int kt = klo;
  for (; kt + 128 < khi; kt += 256)
    kv_tile_pair<MODE>(kbase, vbase, kt, q_base, c, g, qf, l_run, of);
  if (kt < khi)
    kv_tile<MODE>(kbase, vbase, kt, q_base, c, g, qf, l_run, of);
}

__global__ __launch_bounds__(256) void msa_attn16(
    const float* __restrict__ q, const _Float16* __restrict__ KF,
    const _Float16* __restrict__ VF, float* __restrict__ out)
{
  const int tid = threadIdx.x;
  const int lane = tid & 63, w = tid >> 6;          // 4 waves: kv-quarters
  const int c = lane & 15, g = lane >> 4;

  // Dispatch model (FETCH_SIZE r5/r7): XCD = blk%8, CU-mates = {i,i+256,...}.
  // h = i&7 pins each head's 1MB K/V to one XCD's L2.
  // CU-mates vary jj=(i>>8) -> 4 consecutive zigzag spans, work sum in [12,16].
  const int i = blockIdx.x;
  const int h = i & 7;
  const int m = i >> 3;                 // 0..127
  const int jj = m >> 5;                // 0..3  (varies among CU-mates)
  const int sidx = ((m & 7) + jj) & 7;
  const int span = (sidx & 1) ? 7 - (sidx >> 1) : (sidx >> 1);  // zigzag 0,7,1,6,2,5,3,4
  const int sub = ((m >> 3) & 3) * 4 + jj;
  const int q_base = span * SPAN + sub * 32;

  const float* Qh = q + (size_t)h * S_LEN * DH;
  const _Float16* kbase = KF + (size_t)h * 262144 + (size_t)lane * 8;
  const _Float16* vbase = VF + (size_t)h * 262144 + (size_t)lane * 8;
  float* Oh = out + (size_t)h * S_LEN * DH;

  f16x8 qf[2][2];
  #pragma unroll
  for (int grp = 0; grp < 2; ++grp) {
    const float* qp = Qh + (size_t)(q_base + 16 * grp + c) * DH + 8 * g;
    qf[grp][0] = load_cvt8(qp);
    qf[grp][1] = load_cvt8(qp + 32);
  }

  float l_run[2] = {0.f, 0.f};
  f32x4 of[2][4];
  #pragma unroll
  for (int a = 0; a < 2; ++a)
    #pragma unroll
    for (int bb = 0; bb < 4; ++bb) of[a][bb] = (f32x4){0.f, 0.f, 0.f, 0.f};

  const int hist_end = span * SPAN;
  run_range<0>(kbase, vbase, 32 * w, hist_end, q_base, c, g, qf, l_run, of);

  if ((span & 1) == 0) {
    run_range<1>(kbase, vbase, hist_end + 32 * w, q_base + 32, q_base, c, g, qf, l_run, of);
  } else {
    int klo = q_base - 96;
    if (klo < hist_end) klo = hist_end;
    int khi = q_base + 128;
    const int s1 = hist_end + SPAN;
    if (khi > s1) khi = s1;
    run_range<2>(kbase, vbase, klo + 32 * w, khi, q_base, c, g, qf, l_run, of);
  }

  // per-wave row-sum of l across the 4 g-groups
  #pragma unroll
  for (int grp = 0; grp < 2; ++grp) {
    l_run[grp] += __shfl_xor(l_run[grp], 16);
    l_run[grp] += __shfl_xor(l_run[grp], 32);
  }

  // ---- merge the 4 kv-quarter waves in LDS (pure sums) ----
  __shared__ float sl[4][2][16];
  __shared__ float sof[4][2][4][16][17];
  if (g == 0) { sl[w][0][c] = l_run[0]; sl[w][1][c] = l_run[1]; }
  #pragma unroll
  for (int grp = 0; grp < 2; ++grp)
    #pragma unroll
    for (int dd = 0; dd < 4; ++dd)
      #pragma unroll
      for (int r = 0; r < 4; ++r)
        sof[w][grp][dd][4 * g + r][c] = of[grp][dd][r];
  __syncthreads();

  const int mc = tid & 15, mgrp = (tid >> 4) & 1, mdd = (tid >> 5) & 3;
  const int mhalf = tid >> 7;
  float ls = sl[0][mgrp][mc] + sl[1][mgrp][mc] + sl[2][mgrp][mc] + sl[3][mgrp][mc];
  float inv = 1.0f / ls;
  const int row = q_base + 16 * mgrp + mc;
  #pragma unroll
  for (int dbi = 0; dbi < 2; ++dbi) {
    const int db = 2 * mhalf + dbi;
    f32x4 o4;
    #pragma unroll
    for (int j = 0; j < 4; ++j) {
      int dc = db * 4 + j;
      o4[j] = (sof[0][mgrp][mdd][dc][mc] + sof[1][mgrp][mdd][dc][mc]
             + sof[2][mgrp][mdd][dc][mc] + sof[3][mgrp][mdd][dc][mc]) * inv;
    }
    *(f32x4*)(Oh + (size_t)row * DH + mdd * 16 + db * 4) = o4;
  }
}

// ---------------- last-resort fallback (round-1, f32 direct) ----------------
template<int MODE>
__device__ __forceinline__ void kv_tile_fb(
    const float* __restrict__ Kh, const float* __restrict__ Vh,
    int kt, int qg_row, int c, int g,
    const f16x8 (&qf)[2], float& m_run, float& l_run, f32x4 (&of)[4])
{
  f16x8 kf0a = load_cvt8(Kh + (kt +      c) * DH + 8 * g);
  f16x8 kf0b = load_cvt8(Kh + (kt +      c) * DH + 8 * g + 32);
  f16x8 kf1a = load_cvt8(Kh + (kt + 16 + c) * DH + 8 * g);
  f16x8 kf1b = load_cvt8(Kh + (kt + 16 + c) * DH + 8 * g + 32);

  f32x4 st0 = {0.f, 0.f, 0.f, 0.f};
  f32x4 st1 = {0.f, 0.f, 0.f, 0.f};
  st0 = MFMA16(kf0a, qf[0], st0, 0, 0, 0);
  st0 = MFMA16(kf0b, qf[1], st0, 0, 0, 0);
  st1 = MFMA16(kf1a, qf[0], st1, 0, 0, 0);
  st1 = MFMA16(kf1b, qf[1], st1, 0, 0, 0);

  const float SCL = 0.18033688011112042f;
  float ss[8];
  #pragma unroll
  for (int t = 0; t < 2; ++t) {
    #pragma unroll
    for (int r = 0; r < 4; ++r) {
      float vsc = (t ? st1[r] : st0[r]) * SCL;
      if (MODE == 1) {
        int kv = kt + 16 * t + 4 * g + r;
        vsc = (kv <= qg_row) ? vsc : -1e30f;
      } else if (MODE == 2) {
        int kv = kt + 16 * t + 4 * g + r;
        int pq = qg_row & (SPAN - 1), pk = kv & (SPAN - 1);
        int dy = (pq >> 5) - (pk >> 5);
        int dx = (pq & 31) - (pk & 31);
        vsc = (dy * dy + dx * dx <= 6) ? vsc : -1e30f;
      }
      ss[t * 4 + r] = vsc;
    }
  }

  float pmax = ss[0];
  #pragma unroll
  for (int j = 1; j < 8; ++j) pmax = fmaxf(pmax, ss[j]);
  pmax = fmaxf(pmax, __shfl_xor(pmax, 16));
  pmax = fmaxf(pmax, __shfl_xor(pmax, 32));

  float m_new = fmaxf(m_run, pmax);
  float fac = exp2f(m_run - m_new);
  m_run = m_new;

  float p[8];
  float psum = 0.f;
  #pragma unroll
  for (int j = 0; j < 8; ++j) { p[j] = exp2f(ss[j] - m_new); psum += p[j]; }
  psum += __shfl_xor(psum, 16);
  psum += __shfl_xor(psum, 32);
  l_run = l_run * fac + psum;

  float fr0 = __shfl(fac, 4 * g + 0);
  float fr1 = __shfl(fac, 4 * g + 1);
  float fr2 = __shfl(fac, 4 * g + 2);
  float fr3 = __shfl(fac, 4 * g + 3);
  #pragma unroll
  for (int cc = 0; cc < 4; ++cc) {
    of[cc][0] *= fr0; of[cc][1] *= fr1; of[cc][2] *= fr2; of[cc][3] *= fr3;
  }

  f16x8 pa;
  #pragma unroll
  for (int j = 0; j < 8; ++j) pa[j] = (_Float16)p[j];

  #pragma unroll
  for (int cc = 0; cc < 4; ++cc) {
    f16x8 vb;
    #pragma unroll
    for (int j = 0; j < 8; ++j) {
      int kv = kt + ((j < 4) ? (4 * g + j) : (16 + 4 * g + (j - 4)));
      vb[j] = (_Float16)Vh[(size_t)kv * DH + 16 * cc + c];
    }
    of[cc] = MFMA16(pa, vb, of[cc], 0, 0, 0);
  }
}

__global__ __launch_bounds__(64) void msa_attn(
    const float* __restrict__ q, const float* __restrict__ k,
    const float* __restrict__ v, float* __restrict__ out)
{
  const int lane = threadIdx.x;
  const int c = lane & 15, g = lane >> 4;

  const int i = blockIdx.x;
  const int h = i & 7;
  const int grp = (i >> 3) & 31;
  const int t3 = i >> 8;
  const int span = (t3 + grp) & 7;
  const int q_base = span * SPAN + grp * 16;

  const float* Qh = q + (size_t)h * S_LEN * DH;
  const float* Kh = k + (size_t)h * S_LEN * DH;
  const float* Vh = v + (size_t)h * S_LEN * DH;
  float* Oh = out + (size_t)h * S_LEN * DH;

  f16x8 qf[2];
  qf[0] = load_cvt8(Qh + (size_t)(q_base + c) * DH + 8 * g);
  qf[1] = load_cvt8(Qh + (size_t)(q_base + c) * DH + 8 * g + 32);

  float m_run = -1e30f, l_run = 0.f;
  f32x4 of[4] = {{0,0,0,0},{0,0,0,0},{0,0,0,0},{0,0,0,0}};
  const int qg_row = q_base + c;

  const int hist_end = span * SPAN;
  for (int kt = 0; kt < hist_end; kt += 32)
    kv_tile_fb<0>(Kh, Vh, kt, qg_row, c, g, qf, m_run, l_run, of);

  const int s0 = hist_end;
  if ((span & 1) == 0) {
    const int khi = (q_base + 16 + 31) & ~31;
    for (int kt = s0; kt < khi; kt += 32)
      kv_tile_fb<1>(Kh, Vh, kt, qg_row, c, g, qf, m_run, l_run, of);
  } else {
    int klo = (q_base - 66) & ~31;
    if (klo < s0) klo = s0;
    int khi = (q_base + 81 + 32) & ~31;
    const int s1 = s0 + SPAN;
    if (khi > s1) khi = s1;
    for (int kt = klo; kt < khi; kt += 32)
      kv_tile_fb<2>(Kh, Vh, kt, qg_row, c, g, qf, m_run, l_run, of);
  }

  #pragma unroll
  for (int r = 0; r < 4; ++r) {
    float inv = 1.0f / __shfl(l_run, 4 * g + r);
    int row = q_base + 4 * g + r;
    #pragma unroll
    for (int cc = 0; cc < 4; ++cc)
      Oh[(size_t)row * DH + 16 * cc + c] = of[cc][r] * inv;
  }
}

extern "C" void kernel_launch(void* const* d_in, const int* in_sizes, int n_in,
                              void* d_out, int out_size, void* d_ws, size_t ws_size,
                              hipStream_t stream) {
  const float* q = (const float*)d_in[0];
  const float* k = (const float*)d_in[1];
  const float* v = (const float*)d_in[2];
  float* out = (float*)d_out;

  const size_t elems = (size_t)8 * S_LEN * DH;      // 2M f16 each
  const size_t need = elems * 2 * 2;                // KF + VF = 8MB
  if (ws_size >= need) {
    _Float16* KF = (_Float16*)d_ws;
    _Float16* VF = KF + elems;
    prep_frag<<<dim3(1024), dim3(256), 0, stream>>>(k, v, KF, VF);
    msa_attn16<<<dim3(1024), dim3(256), 0, stream>>>(q, KF, VF, out);
  } else {
    msa_attn<<<dim3(2048), dim3(64), 0, stream>>>(q, k, v, out);
  }
}

// Round 17
// 47.474 us; speedup vs baseline: 1.3528x; 1.0531x over previous
//
#include <hip/hip_runtime.h>

#define S_LEN 4096
#define DH 64
#define SPAN 512
#define FIXED_M 8.0f

typedef _Float16 f16x8 __attribute__((ext_vector_type(8)));
typedef __fp16 fp16v2 __attribute__((ext_vector_type(2)));
typedef float f32x4 __attribute__((ext_vector_type(4)));

#define MFMA16 __builtin_amdgcn_mfma_f32_16x16x32_f16

__device__ __forceinline__ f16x8 load_cvt8(const float* __restrict__ p) {
  float4 a = *(const float4*)p;
  float4 b = *(const float4*)(p + 4);
  f16x8 r;
  r[0] = (_Float16)a.x; r[1] = (_Float16)a.y; r[2] = (_Float16)a.z; r[3] = (_Float16)a.w;
  r[4] = (_Float16)b.x; r[5] = (_Float16)b.y; r[6] = (_Float16)b.z; r[7] = (_Float16)b.w;
  return r;
}

// ---------------- pre-pass: fragment-ordered K and V ----------------
//  KF[h][tile][ch 0..3][lane 0..63][8 f16]:
//    ch0: K[32t + c][8g..8g+7]    ch1: K[32t + c][32+8g..]
//    ch2: K[32t+16 + c][8g..]     ch3: K[32t+16 + c][32+8g..]
//  VF[h][tile][dd 0..3][lane][8 f16]: {V[32t+4g+jj][16dd+c]}jj<4, {V[32t+16+4g+jj][16dd+c]}
__global__ __launch_bounds__(256) void prep_frag(const float* __restrict__ k,
                                                 const float* __restrict__ v,
                                                 _Float16* __restrict__ KF,
                                                 _Float16* __restrict__ VF) {
  const int b = blockIdx.x;            // 0..1023
  const int h = b >> 7, tile = b & 127;
  const int kv0 = tile * 32;
  __shared__ _Float16 LK[32][64];      // [kv][d]
  __shared__ _Float16 LV[64][36];      // [d][kv], padded
  const int t = threadIdx.x;
  const int row = t >> 3, cb = (t & 7) * 8;
  {
    const float* kp = k + ((size_t)h * S_LEN + kv0 + row) * DH + cb;
    float4 a = *(const float4*)kp;
    float4 bq = *(const float4*)(kp + 4);
    LK[row][cb + 0] = (_Float16)a.x;  LK[row][cb + 1] = (_Float16)a.y;
    LK[row][cb + 2] = (_Float16)a.z;  LK[row][cb + 3] = (_Float16)a.w;
    LK[row][cb + 4] = (_Float16)bq.x; LK[row][cb + 5] = (_Float16)bq.y;
    LK[row][cb + 6] = (_Float16)bq.z; LK[row][cb + 7] = (_Float16)bq.w;
  }
  {
    const float* vp = v + ((size_t)h * S_LEN + kv0 + row) * DH + cb;
    float4 a = *(const float4*)vp;
    float4 bq = *(const float4*)(vp + 4);
    LV[cb + 0][row] = (_Float16)a.x;  LV[cb + 1][row] = (_Float16)a.y;
    LV[cb + 2][row] = (_Float16)a.z;  LV[cb + 3][row] = (_Float16)a.w;
    LV[cb + 4][row] = (_Float16)bq.x; LV[cb + 5][row] = (_Float16)bq.y;
    LV[cb + 6][row] = (_Float16)bq.z; LV[cb + 7][row] = (_Float16)bq.w;
  }
  __syncthreads();
  const int l = t & 63, c = l & 15, g = l >> 4;
  const size_t tb = (size_t)(h * 128 + tile) * 2048;
  {
    const int ch = t >> 6;
    f16x8 r = *(const f16x8*)&LK[16 * (ch >> 1) + c][32 * (ch & 1) + 8 * g];
    *(f16x8*)(KF + tb + (size_t)(ch * 64 + l) * 8) = r;
  }
  {
    const int dd = t >> 6;
    f16x8 r;
    #pragma unroll
    for (int jj = 0; jj < 4; ++jj) {
      r[jj]     = LV[16 * dd + c][4 * g + jj];
      r[4 + jj] = LV[16 * dd + c][16 + 4 * g + jj];
    }
    *(f16x8*)(VF + tb + (size_t)(dd * 64 + l) * 8) = r;
  }
}

// ---------------- main kernel (round-10 configuration: proven best total) ----------
// Simple loop body, direct loads (compiler pipelines; manual pipelines spill --
// r8/r9), fixed-offset softmax (no max-track / rescale / cross-lane in loop),
// raw v_exp_f32 + packed cvt, zigzag span balance across CU-mates, h=i&7 XCD
// L2 affinity, (256,3) = no spill at VGPR 84.

// MODE: 0 = no mask (history), 1 = causal diag, 2 = spatial diag
template<int MODE>
__device__ __forceinline__ void kv_tile(
    const _Float16* __restrict__ kbase, const _Float16* __restrict__ vbase,
    int kt, int q_base, int c, int g,
    const f16x8 (&qf)[2][2], float (&l_run)[2], f32x4 (&of)[2][4])
{
  const int toff = (kt >> 5) * 2048;   // f16 units
  f16x8 kf0a = *(const f16x8*)(kbase + toff);
  f16x8 kf0b = *(const f16x8*)(kbase + toff + 512);
  f16x8 kf1a = *(const f16x8*)(kbase + toff + 1024);
  f16x8 kf1b = *(const f16x8*)(kbase + toff + 1536);
  f16x8 vf0  = *(const f16x8*)(vbase + toff);
  f16x8 vf1  = *(const f16x8*)(vbase + toff + 512);
  f16x8 vf2  = *(const f16x8*)(vbase + toff + 1024);
  f16x8 vf3  = *(const f16x8*)(vbase + toff + 1536);

  const float SCL = 0.18033688011112042f;  // (1/sqrt(64)) * log2(e)

  #pragma unroll
  for (int grp = 0; grp < 2; ++grp) {
    f32x4 st0 = {0.f, 0.f, 0.f, 0.f};
    f32x4 st1 = {0.f, 0.f, 0.f, 0.f};
    st0 = MFMA16(kf0a, qf[grp][0], st0, 0, 0, 0);
    st0 = MFMA16(kf0b, qf[grp][1], st0, 0, 0, 0);
    st1 = MFMA16(kf1a, qf[grp][0], st1, 0, 0, 0);
    st1 = MFMA16(kf1b, qf[grp][1], st1, 0, 0, 0);
    // S^T[kv = kt + 16t + 4g + r][q = q_base + 16*grp + c]

    const int qg = q_base + 16 * grp + c;
    float p[8];
    #pragma unroll
    for (int t = 0; t < 2; ++t) {
      #pragma unroll
      for (int r = 0; r < 4; ++r) {
        float pe = __builtin_amdgcn_exp2f(fmaf(t ? st1[r] : st0[r], SCL, -FIXED_M));
        if (MODE == 1) {
          int kvi = kt + 16 * t + 4 * g + r;
          pe = (kvi <= qg) ? pe : 0.f;
        } else if (MODE == 2) {
          int kvi = kt + 16 * t + 4 * g + r;
          int pq = qg & (SPAN - 1), pk = kvi & (SPAN - 1);
          int dy = (pq >> 5) - (pk >> 5);
          int dx = (pq & 31) - (pk & 31);
          pe = (dy * dy + dx * dx <= 6) ? pe : 0.f;
        }
        p[4 * t + r] = pe;
      }
    }
    l_run[grp] += ((p[0] + p[1]) + (p[2] + p[3])) + ((p[4] + p[5]) + (p[6] + p[7]));

    union { unsigned int w[4]; f16x8 v; } u;
    union { fp16v2 h; unsigned int w; } t0, t1, t2, t3;
    t0.h = __builtin_amdgcn_cvt_pkrtz(p[0], p[1]);
    t1.h = __builtin_amdgcn_cvt_pkrtz(p[2], p[3]);
    t2.h = __builtin_amdgcn_cvt_pkrtz(p[4], p[5]);
    t3.h = __builtin_amdgcn_cvt_pkrtz(p[6], p[7]);
    u.w[0] = t0.w; u.w[1] = t1.w; u.w[2] = t2.w; u.w[3] = t3.w;
    f16x8 pa = u.v;

    of[grp][0] = MFMA16(vf0, pa, of[grp][0], 0, 0, 0);
    of[grp][1] = MFMA16(vf1, pa, of[grp][1], 0, 0, 0);
    of[grp][2] = MFMA16(vf2, pa, of[grp][2], 0, 0, 0);
    of[grp][3] = MFMA16(vf3, pa, of[grp][3], 0, 0, 0);
  }
}

__global__ __launch_bounds__(256, 3) void msa_attn10(
    const float* __restrict__ q, const _Float16* __restrict__ KF,
    const _Float16* __restrict__ VF, float* __restrict__ out)
{
  const int tid = threadIdx.x;
  const int lane = tid & 63, w = tid >> 6;          // 4 waves: kv-quarters
  const int c = lane & 15, g = lane >> 4;

  // Dispatch model (confirmed by FETCH_SIZE r5/r7): XCD = blk%8, CU-mates = {i,i+256,...}.
  // h = i&7 pins each head's K/V to one XCD's L2.
  // CU-mates vary jj=(i>>8) -> 4 consecutive zigzag spans, work sum in [12,16].
  const int i = blockIdx.x;
  const int h = i & 7;
  const int m = i >> 3;                 // 0..127
  const int jj = m >> 5;                // 0..3  (varies among CU-mates)
  const int sidx = ((m & 7) + jj) & 7;
  const int span = (sidx & 1) ? 7 - (sidx >> 1) : (sidx >> 1);  // zigzag 0,7,1,6,2,5,3,4
  const int sub = ((m >> 3) & 3) * 4 + jj;
  const int q_base = span * SPAN + sub * 32;

  const float* Qh = q + (size_t)h * S_LEN * DH;
  const _Float16* kbase = KF + (size_t)h * 262144 + (size_t)lane * 8;
  const _Float16* vbase = VF + (size_t)h * 262144 + (size_t)lane * 8;
  float* Oh = out + (size_t)h * S_LEN * DH;

  f16x8 qf[2][2];
  #pragma unroll
  for (int grp = 0; grp < 2; ++grp) {
    const float* qp = Qh + (size_t)(q_base + 16 * grp + c) * DH + 8 * g;
    qf[grp][0] = load_cvt8(qp);
    qf[grp][1] = load_cvt8(qp + 32);
  }

  float l_run[2] = {0.f, 0.f};
  f32x4 of[2][4];
  #pragma unroll
  for (int a = 0; a < 2; ++a)
    #pragma unroll
    for (int b = 0; b < 4; ++b) of[a][b] = (f32x4){0.f, 0.f, 0.f, 0.f};

  const int hist_end = span * SPAN;
  // history: fully valid, 4-way kv split (stride 128)
  for (int kt = 32 * w; kt < hist_end; kt += 128)
    kv_tile<0>(kbase, vbase, kt, q_base, c, g, qf, l_run, of);

  if ((span & 1) == 0) {
    for (int kt = hist_end + 32 * w; kt < q_base + 32; kt += 128)
      kv_tile<1>(kbase, vbase, kt, q_base, c, g, qf, l_run, of);
  } else {
    int klo = q_base - 96;           // (q_base-66) floored to 32-multiple
    if (klo < hist_end) klo = hist_end;
    int khi = q_base + 128;          // covers q_base+31+66
    const int s1 = hist_end + SPAN;
    if (khi > s1) khi = s1;
    for (int kt = klo + 32 * w; kt < khi; kt += 128)
      kv_tile<2>(kbase, vbase, kt, q_base, c, g, qf, l_run, of);
  }

  // per-wave row-sum of l across the 4 g-groups
  #pragma unroll
  for (int grp = 0; grp < 2; ++grp) {
    l_run[grp] += __shfl_xor(l_run[grp], 16);
    l_run[grp] += __shfl_xor(l_run[grp], 32);
  }

  // ---- merge the 4 kv-quarter waves in LDS (pure sums) ----
  __shared__ float sl[4][2][16];
  __shared__ float sof[4][2][4][16][17];  // [w][grp][dd][dcomp=4g+r][c], padded
  if (g == 0) { sl[w][0][c] = l_run[0]; sl[w][1][c] = l_run[1]; }
  #pragma unroll
  for (int grp = 0; grp < 2; ++grp)
    #pragma unroll
    for (int dd = 0; dd < 4; ++dd)
      #pragma unroll
      for (int r = 0; r < 4; ++r)
        sof[w][grp][dd][4 * g + r][c] = of[grp][dd][r];
  __syncthreads();

  const int mc = tid & 15, mgrp = (tid >> 4) & 1, mdd = (tid >> 5) & 3;
  const int mhalf = tid >> 7;
  float ls = sl[0][mgrp][mc] + sl[1][mgrp][mc] + sl[2][mgrp][mc] + sl[3][mgrp][mc];
  float inv = 1.0f / ls;
  const int row = q_base + 16 * mgrp + mc;
  #pragma unroll
  for (int dbi = 0; dbi < 2; ++dbi) {
    const int db = 2 * mhalf + dbi;
    f32x4 o4;
    #pragma unroll
    for (int j = 0; j < 4; ++j) {
      int dc = db * 4 + j;
      o4[j] = (sof[0][mgrp][mdd][dc][mc] + sof[1][mgrp][mdd][dc][mc]
             + sof[2][mgrp][mdd][dc][mc] + sof[3][mgrp][mdd][dc][mc]) * inv;
    }
    *(f32x4*)(Oh + (size_t)row * DH + mdd * 16 + db * 4) = o4;
  }
}

// ---------------- fallback (round-1 kernel, f32 direct) ----------------

template<int MODE>
__device__ __forceinline__ void kv_tile_fb(
    const float* __restrict__ Kh, const float* __restrict__ Vh,
    int kt, int qg_row, int c, int g,
    const f16x8 (&qf)[2], float& m_run, float& l_run, f32x4 (&of)[4])
{
  f16x8 kf0a = load_cvt8(Kh + (kt +      c) * DH + 8 * g);
  f16x8 kf0b = load_cvt8(Kh + (kt +      c) * DH + 8 * g + 32);
  f16x8 kf1a = load_cvt8(Kh + (kt + 16 + c) * DH + 8 * g);
  f16x8 kf1b = load_cvt8(Kh + (kt + 16 + c) * DH + 8 * g + 32);

  f32x4 st0 = {0.f, 0.f, 0.f, 0.f};
  f32x4 st1 = {0.f, 0.f, 0.f, 0.f};
  st0 = MFMA16(kf0a, qf[0], st0, 0, 0, 0);
  st0 = MFMA16(kf0b, qf[1], st0, 0, 0, 0);
  st1 = MFMA16(kf1a, qf[0], st1, 0, 0, 0);
  st1 = MFMA16(kf1b, qf[1], st1, 0, 0, 0);

  const float SCL = 0.18033688011112042f;
  float ss[8];
  #pragma unroll
  for (int t = 0; t < 2; ++t) {
    #pragma unroll
    for (int r = 0; r < 4; ++r) {
      float vsc = (t ? st1[r] : st0[r]) * SCL;
      if (MODE == 1) {
        int kv = kt + 16 * t + 4 * g + r;
        vsc = (kv <= qg_row) ? vsc : -1e30f;
      } else if (MODE == 2) {
        int kv = kt + 16 * t + 4 * g + r;
        int pq = qg_row & (SPAN - 1), pk = kv & (SPAN - 1);
        int dy = (pq >> 5) - (pk >> 5);
        int dx = (pq & 31) - (pk & 31);
        vsc = (dy * dy + dx * dx <= 6) ? vsc : -1e30f;
      }
      ss[t * 4 + r] = vsc;
    }
  }

  float pmax = ss[0];
  #pragma unroll
  for (int j = 1; j < 8; ++j) pmax = fmaxf(pmax, ss[j]);
  pmax = fmaxf(pmax, __shfl_xor(pmax, 16));
  pmax = fmaxf(pmax, __shfl_xor(pmax, 32));

  float m_new = fmaxf(m_run, pmax);
  float fac = exp2f(m_run - m_new);
  m_run = m_new;

  float p[8];
  float psum = 0.f;
  #pragma unroll
  for (int j = 0; j < 8; ++j) { p[j] = exp2f(ss[j] - m_new); psum += p[j]; }
  psum += __shfl_xor(psum, 16);
  psum += __shfl_xor(psum, 32);
  l_run = l_run * fac + psum;

  float fr0 = __shfl(fac, 4 * g + 0);
  float fr1 = __shfl(fac, 4 * g + 1);
  float fr2 = __shfl(fac, 4 * g + 2);
  float fr3 = __shfl(fac, 4 * g + 3);
  #pragma unroll
  for (int cc = 0; cc < 4; ++cc) {
    of[cc][0] *= fr0; of[cc][1] *= fr1; of[cc][2] *= fr2; of[cc][3] *= fr3;
  }

  f16x8 pa;
  #pragma unroll
  for (int j = 0; j < 8; ++j) pa[j] = (_Float16)p[j];

  #pragma unroll
  for (int cc = 0; cc < 4; ++cc) {
    f16x8 vb;
    #pragma unroll
    for (int j = 0; j < 8; ++j) {
      int kv = kt + ((j < 4) ? (4 * g + j) : (16 + 4 * g + (j - 4)));
      vb[j] = (_Float16)Vh[(size_t)kv * DH + 16 * cc + c];
    }
    of[cc] = MFMA16(pa, vb, of[cc], 0, 0, 0);
  }
}

__global__ __launch_bounds__(64) void msa_attn(
    const float* __restrict__ q, const float* __restrict__ k,
    const float* __restrict__ v, float* __restrict__ out)
{
  const int lane = threadIdx.x;
  const int c = lane & 15, g = lane >> 4;

  const int i = blockIdx.x;
  const int h = i & 7;
  const int grp = (i >> 3) & 31;
  const int t3 = i >> 8;
  const int span = (t3 + grp) & 7;
  const int q_base = span * SPAN + grp * 16;

  const float* Qh = q + (size_t)h * S_LEN * DH;
  const float* Kh = k + (size_t)h * S_LEN * DH;
  const float* Vh = v + (size_t)h * S_LEN * DH;
  float* Oh = out + (size_t)h * S_LEN * DH;

  f16x8 qf[2];
  qf[0] = load_cvt8(Qh + (size_t)(q_base + c) * DH + 8 * g);
  qf[1] = load_cvt8(Qh + (size_t)(q_base + c) * DH + 8 * g + 32);

  float m_run = -1e30f, l_run = 0.f;
  f32x4 of[4] = {{0,0,0,0},{0,0,0,0},{0,0,0,0},{0,0,0,0}};
  const int qg_row = q_base + c;

  const int hist_end = span * SPAN;
  for (int kt = 0; kt < hist_end; kt += 32)
    kv_tile_fb<0>(Kh, Vh, kt, qg_row, c, g, qf, m_run, l_run, of);

  const int s0 = hist_end;
  if ((span & 1) == 0) {
    const int khi = (q_base + 16 + 31) & ~31;
    for (int kt = s0; kt < khi; kt += 32)
      kv_tile_fb<1>(Kh, Vh, kt, qg_row, c, g, qf, m_run, l_run, of);
  } else {
    int klo = (q_base - 66) & ~31;
    if (klo < s0) klo = s0;
    int khi = (q_base + 81 + 32) & ~31;
    const int s1 = s0 + SPAN;
    if (khi > s1) khi = s1;
    for (int kt = klo; kt < khi; kt += 32)
      kv_tile_fb<2>(Kh, Vh, kt, qg_row, c, g, qf, m_run, l_run, of);
  }

  #pragma unroll
  for (int r = 0; r < 4; ++r) {
    float inv = 1.0f / __shfl(l_run, 4 * g + r);
    int row = q_base + 4 * g + r;
    #pragma unroll
    for (int cc = 0; cc < 4; ++cc)
      Oh[(size_t)row * DH + 16 * cc + c] = of[cc][r] * inv;
  }
}

extern "C" void kernel_launch(void* const* d_in, const int* in_sizes, int n_in,
                              void* d_out, int out_size, void* d_ws, size_t ws_size,
                              hipStream_t stream) {
  const float* q = (const float*)d_in[0];
  const float* k = (const float*)d_in[1];
  const float* v = (const float*)d_in[2];
  float* out = (float*)d_out;

  const size_t elems = (size_t)8 * S_LEN * DH;      // 2M f16 each
  const size_t need = elems * 2 * 2;                // KF + VF = 8MB
  if (ws_size >= need) {
    _Float16* KF = (_Float16*)d_ws;
    _Float16* VF = KF + elems;
    prep_frag<<<dim3(1024), dim3(256), 0, stream>>>(k, v, KF, VF);
    msa_attn10<<<dim3(1024), dim3(256), 0, stream>>>(q, KF, VF, out);
  } else {
    msa_attn<<<dim3(2048), dim3(64), 0, stream>>>(q, k, v, out);
  }
}